// Round 4
// baseline (385.292 us; speedup 1.0000x reference)
//
#include <hip/hip_runtime.h>
#include <hip/hip_bf16.h>

#define NF 20000
#define NH 40000
#define NALL 60000
#define NE 640000
#define DD 128
#define AA 64
#define NB 256
#define KC 64   // out_gemm split-K chunk

// ---------------- helpers ----------------

__device__ __forceinline__ float fast_rcp(float x) {
#if __has_builtin(__builtin_amdgcn_rcpf)
    return __builtin_amdgcn_rcpf(x);
#else
    return 1.f / x;
#endif
}

// tanh(x) = 1 - 2/(exp(2x)+1); exact at +-inf via rcp(inf)=0
__device__ __forceinline__ float tanh_fast(float x) {
    float e = __expf(2.f * x);
    return 1.f - 2.f * fast_rcp(e + 1.f);
}

// ---------------- kernels ----------------

// Detect whether index arrays are int64 (high dwords all zero) or int32.
__global__ void probe_kernel(const unsigned int* __restrict__ fci_raw,
                             int* __restrict__ flag) {
    unsigned int v = fci_raw[threadIdx.x * 2 + 1];
    unsigned long long any = __ballot(v != 0);
    if (threadIdx.x == 0) flag[0] = (any == 0ull) ? 1 : 0;  // 1 => int64
}

__global__ void convert_kernel(const void* __restrict__ cp_raw,
                               const void* __restrict__ fci_raw,
                               int* __restrict__ cp32, int* __restrict__ fci32,
                               const int* __restrict__ flag) {
    int e = blockIdx.x * 256 + threadIdx.x;
    if (e >= NE) return;
    if (flag[0]) {
        cp32[e]  = (int)((const long long*)cp_raw)[e];
        fci32[e] = (int)((const long long*)fci_raw)[e];
    } else {
        cp32[e]  = ((const int*)cp_raw)[e];
        fci32[e] = ((const int*)fci_raw)[e];
    }
}

__global__ void zero_out_kernel(float* __restrict__ out) {
    out[blockIdx.x * 256 + threadIdx.x] = 0.f;
}

// offs[f] = lower_bound(cp32, f) for f in [0, NF]
__global__ void offsets_kernel(const int* __restrict__ cp32, int* __restrict__ offs) {
    int f = blockIdx.x * 256 + threadIdx.x;
    if (f > NF) return;
    int lo = 0, hi = NE;
    while (lo < hi) {
        int mid = (lo + hi) >> 1;
        if (cp32[mid] < f) lo = mid + 1; else hi = mid;
    }
    offs[f] = lo;
}

// P2[i][a] = all_emb[i] @ W2   (blocks [0, NALL/32))
// P1[f][a] = feat_emb[f] @ W1 + bias   (blocks [NALL/32, NALL/32+NF/32))
__global__ __launch_bounds__(256) void proj_kernel(
    const float* __restrict__ feat_emb, const float* __restrict__ hid_emb,
    const float* __restrict__ w_kernel, const float* __restrict__ w_bias,
    float* __restrict__ P1, float* __restrict__ P2)
{
    __shared__ float Wl[128 * 64];      // 32KB: relevant half of w_kernel
    __shared__ float embl[32][128];     // 16KB: 32 embedding rows

    const int blk  = blockIdx.x;
    const bool isP2 = blk < (NALL / 32);
    const int row0 = isP2 ? blk * 32 : (blk - NALL / 32) * 32;
    const int t = threadIdx.x;
    const int kbase = isP2 ? 128 * 64 : 0;   // W2 = rows [128,256), W1 = rows [0,128)

#pragma unroll
    for (int i = 0; i < 32; ++i) {
        int idx = t + i * 256;
        Wl[idx] = w_kernel[kbase + idx];
    }
#pragma unroll
    for (int i = 0; i < 16; ++i) {
        int idx = t + i * 256;
        int r = idx >> 7, c = idx & 127;
        int grow = row0 + r;
        const float* src;
        if (isP2)
            src = (grow < NF) ? (feat_emb + (size_t)grow * DD)
                              : (hid_emb + (size_t)(grow - NF) * DD);
        else
            src = feat_emb + (size_t)grow * DD;
        embl[r][c] = src[c];
    }
    __syncthreads();

    const int a  = t & 63;
    const int rg = t >> 6;   // wave id: rows rg*8 .. rg*8+7
    float acc[8];
#pragma unroll
    for (int j = 0; j < 8; ++j) acc[j] = 0.f;

    for (int k4 = 0; k4 < 32; ++k4) {
        const int k = k4 * 4;
        float w0 = Wl[(k + 0) * 64 + a];
        float w1 = Wl[(k + 1) * 64 + a];
        float w2 = Wl[(k + 2) * 64 + a];
        float w3 = Wl[(k + 3) * 64 + a];
#pragma unroll
        for (int j = 0; j < 8; ++j) {
            const float4 ev = *(const float4*)&embl[rg * 8 + j][k];
            acc[j] = fmaf(ev.x, w0, acc[j]);
            acc[j] = fmaf(ev.y, w1, acc[j]);
            acc[j] = fmaf(ev.z, w2, acc[j]);
            acc[j] = fmaf(ev.w, w3, acc[j]);
        }
    }

    if (isP2) {
#pragma unroll
        for (int j = 0; j < 8; ++j)
            P2[(size_t)(row0 + rg * 8 + j) * AA + a] = acc[j];
    } else {
        float b = w_bias[a];
#pragma unroll
        for (int j = 0; j < 8; ++j)
            P1[(size_t)(row0 + rg * 8 + j) * AA + a] = acc[j] + b;
    }
}

// Fused score + segment-softmax + aggregation, 2-stage software pipeline.
// One wave per feature; within a wave: half = edge parity, 32 lanes per edge.
__global__ __launch_bounds__(256) void fused_agg_kernel(
    const float* __restrict__ feat_emb, const float* __restrict__ hid_emb,
    const float* __restrict__ P1, const float* __restrict__ P2,
    const float* __restrict__ u_kernel, const float* __restrict__ corr,
    const int* __restrict__ offs, const int* __restrict__ fci32,
    float* __restrict__ context)
{
    const int wave = threadIdx.x >> 6;          // 0..3
    const int lane = threadIdx.x & 63;
    const int h = lane >> 5;                    // edge parity
    const int l = lane & 31;
    const int f = blockIdx.x * 4 + wave;
    if (f >= NF) return;

    const int s0 = offs[f], s1 = offs[f + 1];

    const float2 p1v = ((const float2*)(P1 + (size_t)f * AA))[l];
    const float2 uv  = ((const float2*)u_kernel)[l];

    float4 acc = {0.f, 0.f, 0.f, 0.f};
    float den = 0.f;

    int e = s0 + h;
    bool validA = e < s1;
    float crA = 0.f;
    float2 p2A = {0.f, 0.f};
    float4 emA = {0.f, 0.f, 0.f, 0.f};
    if (validA) {
        const int iA = fci32[e];
        crA = corr[e];
        p2A = ((const float2*)(P2 + (size_t)iA * AA))[l];
        const float* src = (iA < NF) ? feat_emb + (size_t)iA * DD
                                     : hid_emb + (size_t)(iA - NF) * DD;
        emA = ((const float4*)src)[l];
    }

    while (validA) {
        const int en = e + 2;
        const bool validB = en < s1;
        float crB = 0.f;
        float2 p2B = {0.f, 0.f};
        float4 emB = {0.f, 0.f, 0.f, 0.f};
        if (validB) {
            const int iB = fci32[en];
            crB = corr[en];
            p2B = ((const float2*)(P2 + (size_t)iB * AA))[l];
            const float* src = (iB < NF) ? feat_emb + (size_t)iB * DD
                                         : hid_emb + (size_t)(iB - NF) * DD;
            emB = ((const float4*)src)[l];
        }

        // score for current (A) while B's gathers are in flight
        float part = fmaf(tanh_fast(p1v.x + p2A.x), uv.x,
                          tanh_fast(p1v.y + p2A.y) * uv.y);
        part += __shfl_xor(part, 1);
        part += __shfl_xor(part, 2);
        part += __shfl_xor(part, 4);
        part += __shfl_xor(part, 8);
        part += __shfl_xor(part, 16);
        const float sc = __expf(part) * crA;

        acc.x = fmaf(sc, emA.x, acc.x);
        acc.y = fmaf(sc, emA.y, acc.y);
        acc.z = fmaf(sc, emA.z, acc.z);
        acc.w = fmaf(sc, emA.w, acc.w);
        den += sc;

        e = en; validA = validB;
        crA = crB; p2A = p2B; emA = emB;
    }

    // combine the two edge-parity halves
    acc.x += __shfl_xor(acc.x, 32);
    acc.y += __shfl_xor(acc.y, 32);
    acc.z += __shfl_xor(acc.z, 32);
    acc.w += __shfl_xor(acc.w, 32);
    den   += __shfl_xor(den, 32);

    if (h == 0) {
        float4 r = {0.f, 0.f, 0.f, 0.f};
        if (s1 > s0) {
            const float inv = 1.f / den;
            r.x = acc.x * inv; r.y = acc.y * inv;
            r.z = acc.z * inv; r.w = acc.w * inv;
        }
        ((float4*)(context + (size_t)f * DD))[l] = r;
    }
}

// out[b][d] += values[b][f] * context[f][d]
// grid: x = 4 b-tiles of 64, y = 313 k-chunks of 64. 8b x 4d register tile.
__global__ __launch_bounds__(256) void out_gemm_kernel(
    const float* __restrict__ values, const float* __restrict__ context,
    float* __restrict__ out)
{
    __shared__ float vl[64][64];    // 16KB values tile [b][k]
    __shared__ float xl[64][128];   // 32KB context tile [k][d]

    const int b0 = blockIdx.x * 64;
    const int k0 = blockIdx.y * KC;
    const int t  = threadIdx.x;
    const int dg = t & 31;          // d = dg*4 .. dg*4+3
    const int bg = t >> 5;          // b = b0 + bg*8 .. +7

    // stage values tile: 1024 float4 slots, 4 per thread (coalesced along k)
#pragma unroll
    for (int it = 0; it < 4; ++it) {
        int idx = t + it * 256;          // 0..1023
        int bb = idx >> 4;               // 0..63
        int kq = idx & 15;               // 0..15
        int kg = k0 + kq * 4;
        float4 v = {0.f, 0.f, 0.f, 0.f};
        if (kg + 3 < NF) {
            v = *(const float4*)&values[(size_t)(b0 + bb) * NF + kg];
        } else {
            const float* row = &values[(size_t)(b0 + bb) * NF];
            if (kg + 0 < NF) v.x = row[kg + 0];
            if (kg + 1 < NF) v.y = row[kg + 1];
            if (kg + 2 < NF) v.z = row[kg + 2];
        }
        *(float4*)&vl[bb][kq * 4] = v;
    }
    // stage context tile: 2048 float4 slots, 8 per thread (coalesced along d)
#pragma unroll
    for (int it = 0; it < 8; ++it) {
        int idx = t + it * 256;          // 0..2047
        int kk = idx >> 5;               // 0..63
        int c4 = (idx & 31) * 4;
        float4 v = {0.f, 0.f, 0.f, 0.f};
        int kg = k0 + kk;
        if (kg < NF) v = *(const float4*)&context[(size_t)kg * DD + c4];
        *(float4*)&xl[kk][c4] = v;
    }
    __syncthreads();

    float4 acc[8];
#pragma unroll
    for (int i = 0; i < 8; ++i) acc[i] = (float4){0.f, 0.f, 0.f, 0.f};

    for (int k4 = 0; k4 < 16; ++k4) {
        const float4 xv0 = *(const float4*)&xl[k4 * 4 + 0][dg * 4];
        const float4 xv1 = *(const float4*)&xl[k4 * 4 + 1][dg * 4];
        const float4 xv2 = *(const float4*)&xl[k4 * 4 + 2][dg * 4];
        const float4 xv3 = *(const float4*)&xl[k4 * 4 + 3][dg * 4];
#pragma unroll
        for (int i = 0; i < 8; ++i) {
            const float4 vv = *(const float4*)&vl[bg * 8 + i][k4 * 4];
            acc[i].x = fmaf(vv.x, xv0.x, acc[i].x);
            acc[i].y = fmaf(vv.x, xv0.y, acc[i].y);
            acc[i].z = fmaf(vv.x, xv0.z, acc[i].z);
            acc[i].w = fmaf(vv.x, xv0.w, acc[i].w);
            acc[i].x = fmaf(vv.y, xv1.x, acc[i].x);
            acc[i].y = fmaf(vv.y, xv1.y, acc[i].y);
            acc[i].z = fmaf(vv.y, xv1.z, acc[i].z);
            acc[i].w = fmaf(vv.y, xv1.w, acc[i].w);
            acc[i].x = fmaf(vv.z, xv2.x, acc[i].x);
            acc[i].y = fmaf(vv.z, xv2.y, acc[i].y);
            acc[i].z = fmaf(vv.z, xv2.z, acc[i].z);
            acc[i].w = fmaf(vv.z, xv2.w, acc[i].w);
            acc[i].x = fmaf(vv.w, xv3.x, acc[i].x);
            acc[i].y = fmaf(vv.w, xv3.y, acc[i].y);
            acc[i].z = fmaf(vv.w, xv3.z, acc[i].z);
            acc[i].w = fmaf(vv.w, xv3.w, acc[i].w);
        }
    }

#pragma unroll
    for (int i = 0; i < 8; ++i) {
        float* o = &out[(size_t)(b0 + bg * 8 + i) * DD + dg * 4];
        atomicAdd(o + 0, acc[i].x);
        atomicAdd(o + 1, acc[i].y);
        atomicAdd(o + 2, acc[i].z);
        atomicAdd(o + 3, acc[i].w);
    }
}

// ---------------- launch ----------------

extern "C" void kernel_launch(void* const* d_in, const int* in_sizes, int n_in,
                              void* d_out, int out_size, void* d_ws, size_t ws_size,
                              hipStream_t stream) {
    const float* values   = (const float*)d_in[0];
    const float* feat_emb = (const float*)d_in[1];
    const float* hid_emb  = (const float*)d_in[2];
    const float* w_kernel = (const float*)d_in[3];
    const float* w_bias   = (const float*)d_in[4];
    const float* u_kernel = (const float*)d_in[5];
    const float* corr     = (const float*)d_in[6];
    const void*  cp_raw   = d_in[7];
    const void*  fci_raw  = d_in[8];
    float* out = (float*)d_out;

    char* ws = (char*)d_ws;
    size_t off = 0;
    auto alloc = [&](size_t bytes) {
        size_t cur = off;
        off += (bytes + 511) & ~size_t(511);
        return cur;
    };
    int*   flag    = (int*)  (ws + alloc(4));
    int*   cp32    = (int*)  (ws + alloc(sizeof(int) * NE));
    int*   fci32   = (int*)  (ws + alloc(sizeof(int) * NE));
    int*   offs    = (int*)  (ws + alloc(sizeof(int) * (NF + 1)));
    float* P1      = (float*)(ws + alloc(sizeof(float) * (size_t)NF * AA));
    float* P2      = (float*)(ws + alloc(sizeof(float) * (size_t)NALL * AA));
    float* context = (float*)(ws + alloc(sizeof(float) * (size_t)NF * DD));

    // 1. dtype probe + index conversion
    probe_kernel<<<1, 64, 0, stream>>>((const unsigned int*)fci_raw, flag);
    convert_kernel<<<(NE + 255) / 256, 256, 0, stream>>>(cp_raw, fci_raw, cp32, fci32, flag);

    // 2. zero the atomic output
    zero_out_kernel<<<(NB * DD) / 256, 256, 0, stream>>>(out);

    // 3. projections P1 / P2
    proj_kernel<<<NALL / 32 + NF / 32, 256, 0, stream>>>(feat_emb, hid_emb, w_kernel,
                                                         w_bias, P1, P2);

    // 4. segment offsets
    offsets_kernel<<<(NF + 1 + 255) / 256, 256, 0, stream>>>(cp32, offs);

    // 5. fused score + segment softmax + weighted aggregation -> context
    fused_agg_kernel<<<(NF + 3) / 4, 256, 0, stream>>>(feat_emb, hid_emb, P1, P2,
                                                       u_kernel, corr, offs, fci32,
                                                       context);

    // 6. out = values @ context  (split-K, 1252 blocks)
    dim3 ggrid(NB / 64, (NF + KC - 1) / KC);
    out_gemm_kernel<<<ggrid, 256, 0, stream>>>(values, context, out);
}

// Round 5
// 259.695 us; speedup vs baseline: 1.4836x; 1.4836x over previous
//
#include <hip/hip_runtime.h>
#include <hip/hip_bf16.h>

#define NF 20000
#define NH 40000
#define NALL 60000
#define NE 640000
#define DD 128
#define AA 64
#define NB 256
#define NSPLIT 128   // out_gemm split-K slices (atomic-free two-stage)

// ---------------- helpers ----------------

__device__ __forceinline__ float fast_rcp(float x) {
#if __has_builtin(__builtin_amdgcn_rcpf)
    return __builtin_amdgcn_rcpf(x);
#else
    return 1.f / x;
#endif
}

// tanh(x) = 1 - 2/(exp(2x)+1); exact at +-inf via rcp(inf)=0
__device__ __forceinline__ float tanh_fast(float x) {
    float e = __expf(2.f * x);
    return 1.f - 2.f * fast_rcp(e + 1.f);
}

// ---------------- kernels ----------------

// Detect whether index arrays are int64 (high dwords all zero) or int32.
__global__ void probe_kernel(const unsigned int* __restrict__ fci_raw,
                             int* __restrict__ flag) {
    unsigned int v = fci_raw[threadIdx.x * 2 + 1];
    unsigned long long any = __ballot(v != 0);
    if (threadIdx.x == 0) flag[0] = (any == 0ull) ? 1 : 0;  // 1 => int64
}

__global__ void convert_kernel(const void* __restrict__ cp_raw,
                               const void* __restrict__ fci_raw,
                               int* __restrict__ cp32, int* __restrict__ fci32,
                               const int* __restrict__ flag) {
    int e = blockIdx.x * 256 + threadIdx.x;
    if (e >= NE) return;
    if (flag[0]) {
        cp32[e]  = (int)((const long long*)cp_raw)[e];
        fci32[e] = (int)((const long long*)fci_raw)[e];
    } else {
        cp32[e]  = ((const int*)cp_raw)[e];
        fci32[e] = ((const int*)fci_raw)[e];
    }
}

// offs[f] = lower_bound(cp32, f) for f in [0, NF]
__global__ void offsets_kernel(const int* __restrict__ cp32, int* __restrict__ offs) {
    int f = blockIdx.x * 256 + threadIdx.x;
    if (f > NF) return;
    int lo = 0, hi = NE;
    while (lo < hi) {
        int mid = (lo + hi) >> 1;
        if (cp32[mid] < f) lo = mid + 1; else hi = mid;
    }
    offs[f] = lo;
}

// P2[i][a] = all_emb[i] @ W2   (blocks [0, NALL/32))
// P1[f][a] = feat_emb[f] @ W1 + bias   (blocks [NALL/32, NALL/32+NF/32))
__global__ __launch_bounds__(256) void proj_kernel(
    const float* __restrict__ feat_emb, const float* __restrict__ hid_emb,
    const float* __restrict__ w_kernel, const float* __restrict__ w_bias,
    float* __restrict__ P1, float* __restrict__ P2)
{
    __shared__ float Wl[128 * 64];      // 32KB: relevant half of w_kernel
    __shared__ float embl[32][128];     // 16KB: 32 embedding rows

    const int blk  = blockIdx.x;
    const bool isP2 = blk < (NALL / 32);
    const int row0 = isP2 ? blk * 32 : (blk - NALL / 32) * 32;
    const int t = threadIdx.x;
    const int kbase = isP2 ? 128 * 64 : 0;   // W2 = rows [128,256), W1 = rows [0,128)

#pragma unroll
    for (int i = 0; i < 32; ++i) {
        int idx = t + i * 256;
        Wl[idx] = w_kernel[kbase + idx];
    }
#pragma unroll
    for (int i = 0; i < 16; ++i) {
        int idx = t + i * 256;
        int r = idx >> 7, c = idx & 127;
        int grow = row0 + r;
        const float* src;
        if (isP2)
            src = (grow < NF) ? (feat_emb + (size_t)grow * DD)
                              : (hid_emb + (size_t)(grow - NF) * DD);
        else
            src = feat_emb + (size_t)grow * DD;
        embl[r][c] = src[c];
    }
    __syncthreads();

    const int a  = t & 63;
    const int rg = t >> 6;   // wave id: rows rg*8 .. rg*8+7
    float acc[8];
#pragma unroll
    for (int j = 0; j < 8; ++j) acc[j] = 0.f;

    for (int k4 = 0; k4 < 32; ++k4) {
        const int k = k4 * 4;
        float w0 = Wl[(k + 0) * 64 + a];
        float w1 = Wl[(k + 1) * 64 + a];
        float w2 = Wl[(k + 2) * 64 + a];
        float w3 = Wl[(k + 3) * 64 + a];
#pragma unroll
        for (int j = 0; j < 8; ++j) {
            const float4 ev = *(const float4*)&embl[rg * 8 + j][k];
            acc[j] = fmaf(ev.x, w0, acc[j]);
            acc[j] = fmaf(ev.y, w1, acc[j]);
            acc[j] = fmaf(ev.z, w2, acc[j]);
            acc[j] = fmaf(ev.w, w3, acc[j]);
        }
    }

    if (isP2) {
#pragma unroll
        for (int j = 0; j < 8; ++j)
            P2[(size_t)(row0 + rg * 8 + j) * AA + a] = acc[j];
    } else {
        float b = w_bias[a];
#pragma unroll
        for (int j = 0; j < 8; ++j)
            P1[(size_t)(row0 + rg * 8 + j) * AA + a] = acc[j] + b;
    }
}

// Fused score + segment-softmax + aggregation, 2-stage software pipeline.
// One wave per feature; within a wave: half = edge parity, 32 lanes per edge.
__global__ __launch_bounds__(256) void fused_agg_kernel(
    const float* __restrict__ feat_emb, const float* __restrict__ hid_emb,
    const float* __restrict__ P1, const float* __restrict__ P2,
    const float* __restrict__ u_kernel, const float* __restrict__ corr,
    const int* __restrict__ offs, const int* __restrict__ fci32,
    float* __restrict__ context)
{
    const int wave = threadIdx.x >> 6;          // 0..3
    const int lane = threadIdx.x & 63;
    const int h = lane >> 5;                    // edge parity
    const int l = lane & 31;
    const int f = blockIdx.x * 4 + wave;
    if (f >= NF) return;

    const int s0 = offs[f], s1 = offs[f + 1];

    const float2 p1v = ((const float2*)(P1 + (size_t)f * AA))[l];
    const float2 uv  = ((const float2*)u_kernel)[l];

    float4 acc = {0.f, 0.f, 0.f, 0.f};
    float den = 0.f;

    int e = s0 + h;
    bool validA = e < s1;
    float crA = 0.f;
    float2 p2A = {0.f, 0.f};
    float4 emA = {0.f, 0.f, 0.f, 0.f};
    if (validA) {
        const int iA = fci32[e];
        crA = corr[e];
        p2A = ((const float2*)(P2 + (size_t)iA * AA))[l];
        const float* src = (iA < NF) ? feat_emb + (size_t)iA * DD
                                     : hid_emb + (size_t)(iA - NF) * DD;
        emA = ((const float4*)src)[l];
    }

    while (validA) {
        const int en = e + 2;
        const bool validB = en < s1;
        float crB = 0.f;
        float2 p2B = {0.f, 0.f};
        float4 emB = {0.f, 0.f, 0.f, 0.f};
        if (validB) {
            const int iB = fci32[en];
            crB = corr[en];
            p2B = ((const float2*)(P2 + (size_t)iB * AA))[l];
            const float* src = (iB < NF) ? feat_emb + (size_t)iB * DD
                                         : hid_emb + (size_t)(iB - NF) * DD;
            emB = ((const float4*)src)[l];
        }

        // score for current (A) while B's gathers are in flight
        float part = fmaf(tanh_fast(p1v.x + p2A.x), uv.x,
                          tanh_fast(p1v.y + p2A.y) * uv.y);
        part += __shfl_xor(part, 1);
        part += __shfl_xor(part, 2);
        part += __shfl_xor(part, 4);
        part += __shfl_xor(part, 8);
        part += __shfl_xor(part, 16);
        const float sc = __expf(part) * crA;

        acc.x = fmaf(sc, emA.x, acc.x);
        acc.y = fmaf(sc, emA.y, acc.y);
        acc.z = fmaf(sc, emA.z, acc.z);
        acc.w = fmaf(sc, emA.w, acc.w);
        den += sc;

        e = en; validA = validB;
        crA = crB; p2A = p2B; emA = emB;
    }

    // combine the two edge-parity halves
    acc.x += __shfl_xor(acc.x, 32);
    acc.y += __shfl_xor(acc.y, 32);
    acc.z += __shfl_xor(acc.z, 32);
    acc.w += __shfl_xor(acc.w, 32);
    den   += __shfl_xor(den, 32);

    if (h == 0) {
        float4 r = {0.f, 0.f, 0.f, 0.f};
        if (s1 > s0) {
            const float inv = 1.f / den;
            r.x = acc.x * inv; r.y = acc.y * inv;
            r.z = acc.z * inv; r.w = acc.w * inv;
        }
        ((float4*)(context + (size_t)f * DD))[l] = r;
    }
}

// Stage 1: partial[sy][b][d] = sum over this slice's k of values[b][k]*context[k][d]
// grid: (4 b-tiles of 64, NSPLIT k-slices). Register tile 8b x 4d. NO atomics.
__global__ __launch_bounds__(256) void out_gemm_partial(
    const float* __restrict__ values, const float* __restrict__ context,
    float* __restrict__ partial)
{
    __shared__ float vl[64][64];    // 16KB values tile [b][k]
    __shared__ float xl[64][128];   // 32KB context tile [k][d]

    const int b0 = blockIdx.x * 64;
    const int sy = blockIdx.y;
    // k-range of this slice, in float4 units (5000 total; NF = 5000*4 exactly)
    const int s0_4 = (sy * 5000) >> 7;        // /NSPLIT
    const int s1_4 = ((sy + 1) * 5000) >> 7;
    const int t  = threadIdx.x;
    const int dg = t & 31;          // d = dg*4 .. dg*4+3
    const int bg = t >> 5;          // b = b0 + bg*8 .. +7

    float4 acc[8];
#pragma unroll
    for (int i = 0; i < 8; ++i) acc[i] = (float4){0.f, 0.f, 0.f, 0.f};

    for (int t4 = s0_4; t4 < s1_4; t4 += 16) {
        const int kt4 = min(16, s1_4 - t4);   // float4 units in this tile
        __syncthreads();
        // stage values tile: slots (bb, kq), kq in f4 units, coalesced along k
#pragma unroll
        for (int it = 0; it < 4; ++it) {
            int idx = t + it * 256;          // 0..1023
            int bb = idx >> 4;               // 0..63
            int kq = idx & 15;               // 0..15
            if (kq < kt4)
                *(float4*)&vl[bb][kq * 4] =
                    *(const float4*)&values[(size_t)(b0 + bb) * NF + (t4 + kq) * 4];
        }
        // stage context tile: rows kk (k within tile), coalesced along d
#pragma unroll
        for (int it = 0; it < 8; ++it) {
            int idx = t + it * 256;          // 0..2047
            int kk = idx >> 5;               // 0..63
            int c4 = (idx & 31) * 4;
            if (kk < kt4 * 4)
                *(float4*)&xl[kk][c4] =
                    *(const float4*)&context[(size_t)(t4 * 4 + kk) * DD + c4];
        }
        __syncthreads();

        for (int k4 = 0; k4 < kt4; ++k4) {
            const float4 xv0 = *(const float4*)&xl[k4 * 4 + 0][dg * 4];
            const float4 xv1 = *(const float4*)&xl[k4 * 4 + 1][dg * 4];
            const float4 xv2 = *(const float4*)&xl[k4 * 4 + 2][dg * 4];
            const float4 xv3 = *(const float4*)&xl[k4 * 4 + 3][dg * 4];
#pragma unroll
            for (int i = 0; i < 8; ++i) {
                const float4 vv = *(const float4*)&vl[bg * 8 + i][k4 * 4];
                acc[i].x = fmaf(vv.x, xv0.x, acc[i].x);
                acc[i].y = fmaf(vv.x, xv0.y, acc[i].y);
                acc[i].z = fmaf(vv.x, xv0.z, acc[i].z);
                acc[i].w = fmaf(vv.x, xv0.w, acc[i].w);
                acc[i].x = fmaf(vv.y, xv1.x, acc[i].x);
                acc[i].y = fmaf(vv.y, xv1.y, acc[i].y);
                acc[i].z = fmaf(vv.y, xv1.z, acc[i].z);
                acc[i].w = fmaf(vv.y, xv1.w, acc[i].w);
                acc[i].x = fmaf(vv.z, xv2.x, acc[i].x);
                acc[i].y = fmaf(vv.z, xv2.y, acc[i].y);
                acc[i].z = fmaf(vv.z, xv2.z, acc[i].z);
                acc[i].w = fmaf(vv.z, xv2.w, acc[i].w);
                acc[i].x = fmaf(vv.w, xv3.x, acc[i].x);
                acc[i].y = fmaf(vv.w, xv3.y, acc[i].y);
                acc[i].z = fmaf(vv.w, xv3.z, acc[i].z);
                acc[i].w = fmaf(vv.w, xv3.w, acc[i].w);
            }
        }
    }

    // private partial store — plain coalesced float4 stores, no contention
    float* pbase = partial + (size_t)sy * (NB * DD);
#pragma unroll
    for (int i = 0; i < 8; ++i)
        *(float4*)&pbase[(size_t)(b0 + bg * 8 + i) * DD + dg * 4] = acc[i];
}

// Stage 2: out[idx] = sum_s partial[s][idx]. One thread per output, no atomics.
// grid: 256 blocks x 128 threads = 32768 threads (uses all CUs).
__global__ __launch_bounds__(128) void out_reduce_kernel(
    const float* __restrict__ partial, float* __restrict__ out)
{
    const int idx = blockIdx.x * 128 + threadIdx.x;
    float s = 0.f;
#pragma unroll 8
    for (int p = 0; p < NSPLIT; ++p)
        s += partial[(size_t)p * (NB * DD) + idx];
    out[idx] = s;
}

// ---------------- launch ----------------

extern "C" void kernel_launch(void* const* d_in, const int* in_sizes, int n_in,
                              void* d_out, int out_size, void* d_ws, size_t ws_size,
                              hipStream_t stream) {
    const float* values   = (const float*)d_in[0];
    const float* feat_emb = (const float*)d_in[1];
    const float* hid_emb  = (const float*)d_in[2];
    const float* w_kernel = (const float*)d_in[3];
    const float* w_bias   = (const float*)d_in[4];
    const float* u_kernel = (const float*)d_in[5];
    const float* corr     = (const float*)d_in[6];
    const void*  cp_raw   = d_in[7];
    const void*  fci_raw  = d_in[8];
    float* out = (float*)d_out;

    char* ws = (char*)d_ws;
    size_t off = 0;
    auto alloc = [&](size_t bytes) {
        size_t cur = off;
        off += (bytes + 511) & ~size_t(511);
        return cur;
    };
    int*   flag    = (int*)  (ws + alloc(4));
    int*   cp32    = (int*)  (ws + alloc(sizeof(int) * NE));
    int*   fci32   = (int*)  (ws + alloc(sizeof(int) * NE));
    int*   offs    = (int*)  (ws + alloc(sizeof(int) * (NF + 1)));
    float* P1      = (float*)(ws + alloc(sizeof(float) * (size_t)NF * AA));
    float* P2      = (float*)(ws + alloc(sizeof(float) * (size_t)NALL * AA));
    float* context = (float*)(ws + alloc(sizeof(float) * (size_t)NF * DD));
    float* partial = (float*)(ws + alloc(sizeof(float) * (size_t)NSPLIT * NB * DD));

    // 1. dtype probe + index conversion
    probe_kernel<<<1, 64, 0, stream>>>((const unsigned int*)fci_raw, flag);
    convert_kernel<<<(NE + 255) / 256, 256, 0, stream>>>(cp_raw, fci_raw, cp32, fci32, flag);

    // 2. projections P1 / P2
    proj_kernel<<<NALL / 32 + NF / 32, 256, 0, stream>>>(feat_emb, hid_emb, w_kernel,
                                                         w_bias, P1, P2);

    // 3. segment offsets
    offsets_kernel<<<(NF + 1 + 255) / 256, 256, 0, stream>>>(cp32, offs);

    // 4. fused score + segment softmax + weighted aggregation -> context
    fused_agg_kernel<<<(NF + 3) / 4, 256, 0, stream>>>(feat_emb, hid_emb, P1, P2,
                                                       u_kernel, corr, offs, fci32,
                                                       context);

    // 5. out = values @ context  (atomic-free two-stage split-K)
    dim3 ggrid(NB / 64, NSPLIT);
    out_gemm_partial<<<ggrid, 256, 0, stream>>>(values, context, partial);
    out_reduce_kernel<<<(NB * DD) / 128, 128, 0, stream>>>(partial, out);
}

// Round 6
// 253.828 us; speedup vs baseline: 1.5179x; 1.0231x over previous
//
#include <hip/hip_runtime.h>
#include <hip/hip_bf16.h>

#define NF 20000
#define NH 40000
#define NALL 60000
#define NE 640000
#define DD 128
#define AA 64
#define NB 256
#define NSPLIT 128   // out_gemm split-K slices (atomic-free two-stage)

// ---------------- helpers ----------------

__device__ __forceinline__ float fast_rcp(float x) {
#if __has_builtin(__builtin_amdgcn_rcpf)
    return __builtin_amdgcn_rcpf(x);
#else
    return 1.f / x;
#endif
}

// tanh(x) = 1 - 2/(exp(2x)+1); exact at +-inf via rcp(inf)=0
__device__ __forceinline__ float tanh_fast(float x) {
    float e = __expf(2.f * x);
    return 1.f - 2.f * fast_rcp(e + 1.f);
}

// ---------------- kernels ----------------

// Detect whether index arrays are int64 (high dwords all zero) or int32.
__global__ void probe_kernel(const unsigned int* __restrict__ fci_raw,
                             int* __restrict__ flag) {
    unsigned int v = fci_raw[threadIdx.x * 2 + 1];
    unsigned long long any = __ballot(v != 0);
    if (threadIdx.x == 0) flag[0] = (any == 0ull) ? 1 : 0;  // 1 => int64
}

__global__ void convert_kernel(const void* __restrict__ cp_raw,
                               const void* __restrict__ fci_raw,
                               int* __restrict__ cp32, int* __restrict__ fci32,
                               const int* __restrict__ flag) {
    int e = blockIdx.x * 256 + threadIdx.x;
    if (e >= NE) return;
    if (flag[0]) {
        cp32[e]  = (int)((const long long*)cp_raw)[e];
        fci32[e] = (int)((const long long*)fci_raw)[e];
    } else {
        cp32[e]  = ((const int*)cp_raw)[e];
        fci32[e] = ((const int*)fci_raw)[e];
    }
}

// offs[f] = lower_bound(cp32, f) for f in [0, NF]
__global__ void offsets_kernel(const int* __restrict__ cp32, int* __restrict__ offs) {
    int f = blockIdx.x * 256 + threadIdx.x;
    if (f > NF) return;
    int lo = 0, hi = NE;
    while (lo < hi) {
        int mid = (lo + hi) >> 1;
        if (cp32[mid] < f) lo = mid + 1; else hi = mid;
    }
    offs[f] = lo;
}

// P2[i][a] = all_emb[i] @ W2   (blocks [0, NALL/32))
// P1[f][a] = feat_emb[f] @ W1 + bias   (blocks [NALL/32, NALL/32+NF/32))
__global__ __launch_bounds__(256) void proj_kernel(
    const float* __restrict__ feat_emb, const float* __restrict__ hid_emb,
    const float* __restrict__ w_kernel, const float* __restrict__ w_bias,
    float* __restrict__ P1, float* __restrict__ P2)
{
    __shared__ float Wl[128 * 64];      // 32KB: relevant half of w_kernel
    __shared__ float embl[32][128];     // 16KB: 32 embedding rows

    const int blk  = blockIdx.x;
    const bool isP2 = blk < (NALL / 32);
    const int row0 = isP2 ? blk * 32 : (blk - NALL / 32) * 32;
    const int t = threadIdx.x;
    const int kbase = isP2 ? 128 * 64 : 0;   // W2 = rows [128,256), W1 = rows [0,128)

#pragma unroll
    for (int i = 0; i < 32; ++i) {
        int idx = t + i * 256;
        Wl[idx] = w_kernel[kbase + idx];
    }
#pragma unroll
    for (int i = 0; i < 16; ++i) {
        int idx = t + i * 256;
        int r = idx >> 7, c = idx & 127;
        int grow = row0 + r;
        const float* src;
        if (isP2)
            src = (grow < NF) ? (feat_emb + (size_t)grow * DD)
                              : (hid_emb + (size_t)(grow - NF) * DD);
        else
            src = feat_emb + (size_t)grow * DD;
        embl[r][c] = src[c];
    }
    __syncthreads();

    const int a  = t & 63;
    const int rg = t >> 6;   // wave id: rows rg*8 .. rg*8+7
    float acc[8];
#pragma unroll
    for (int j = 0; j < 8; ++j) acc[j] = 0.f;

    for (int k4 = 0; k4 < 32; ++k4) {
        const int k = k4 * 4;
        float w0 = Wl[(k + 0) * 64 + a];
        float w1 = Wl[(k + 1) * 64 + a];
        float w2 = Wl[(k + 2) * 64 + a];
        float w3 = Wl[(k + 3) * 64 + a];
#pragma unroll
        for (int j = 0; j < 8; ++j) {
            const float4 ev = *(const float4*)&embl[rg * 8 + j][k];
            acc[j] = fmaf(ev.x, w0, acc[j]);
            acc[j] = fmaf(ev.y, w1, acc[j]);
            acc[j] = fmaf(ev.z, w2, acc[j]);
            acc[j] = fmaf(ev.w, w3, acc[j]);
        }
    }

    if (isP2) {
#pragma unroll
        for (int j = 0; j < 8; ++j)
            P2[(size_t)(row0 + rg * 8 + j) * AA + a] = acc[j];
    } else {
        float b = w_bias[a];
#pragma unroll
        for (int j = 0; j < 8; ++j)
            P1[(size_t)(row0 + rg * 8 + j) * AA + a] = acc[j] + b;
    }
}

// Fused score + segment-softmax + aggregation.
// One wave per feature; h = edge parity (2 edges in flight), 32 lanes per edge.
// Indices/corr come from a register-resident 32-edge chunk loaded coalesced once;
// inner loop has NO index loads on the critical path and is branchless via cr=0
// masking (a masked edge contributes exactly 0 to acc and den).
__global__ __launch_bounds__(256) void fused_agg_kernel(
    const float* __restrict__ feat_emb, const float* __restrict__ hid_emb,
    const float* __restrict__ P1, const float* __restrict__ P2,
    const float* __restrict__ u_kernel, const float* __restrict__ corr,
    const int* __restrict__ offs, const int* __restrict__ fci32,
    float* __restrict__ context)
{
    const int wave = threadIdx.x >> 6;          // 0..3
    const int lane = threadIdx.x & 63;
    const int h = lane >> 5;                    // edge parity
    const int l = lane & 31;
    const int f = blockIdx.x * 4 + wave;
    if (f >= NF) return;

    const int s0 = offs[f], s1 = offs[f + 1];

    const float2 p1v = ((const float2*)(P1 + (size_t)f * AA))[l];
    const float2 uv  = ((const float2*)u_kernel)[l];

    float4 acc = {0.f, 0.f, 0.f, 0.f};
    float den = 0.f;

    for (int cb = s0; cb < s1; cb += 32) {
        const int clen = min(32, s1 - cb);
        // cooperative, coalesced chunk load (both halves load the same 32 edges)
        int   idxr = 0;
        float crr  = 0.f;
        if (l < clen) {
            idxr = fci32[cb + l];
            crr  = corr[cb + l];
        }
        const int nit = (clen - h + 1) >> 1;    // edges e = cb + 2t + h, t < nit
        if (nit <= 0) continue;                 // h=1 with clen==1

        // prologue: edge t=0 (j = h < clen guaranteed since nit > 0)
        int   iA  = __shfl(idxr, h);
        float crA = __shfl(crr, h);
        float2 p2A = ((const float2*)(P2 + (size_t)iA * AA))[l];
        const float* srcA = (iA < NF) ? feat_emb + (size_t)iA * DD
                                      : hid_emb + (size_t)(iA - NF) * DD;
        float4 emA = ((const float4*)srcA)[l];

        for (int t = 0; t < nit; ++t) {
            // prefetch edge t+1 (index via shfl broadcast — no memory dependency)
            const int jn = 2 * (t + 1) + h;
            const bool vB = jn < clen;
            int   iB  = __shfl(idxr, jn & 31);
            float crB = vB ? __shfl(crr, jn & 31) : 0.f;
            if (!vB) iB = iA;                    // keep address valid & cache-hot
            float2 p2B = ((const float2*)(P2 + (size_t)iB * AA))[l];
            const float* srcB = (iB < NF) ? feat_emb + (size_t)iB * DD
                                          : hid_emb + (size_t)(iB - NF) * DD;
            float4 emB = ((const float4*)srcB)[l];

            // score for current edge (A) while B's gathers are in flight
            float part = fmaf(tanh_fast(p1v.x + p2A.x), uv.x,
                              tanh_fast(p1v.y + p2A.y) * uv.y);
            part += __shfl_xor(part, 1);
            part += __shfl_xor(part, 2);
            part += __shfl_xor(part, 4);
            part += __shfl_xor(part, 8);
            part += __shfl_xor(part, 16);
            const float sc = __expf(part) * crA;

            acc.x = fmaf(sc, emA.x, acc.x);
            acc.y = fmaf(sc, emA.y, acc.y);
            acc.z = fmaf(sc, emA.z, acc.z);
            acc.w = fmaf(sc, emA.w, acc.w);
            den += sc;

            iA = iB; crA = crB; p2A = p2B; emA = emB;
        }
    }

    // combine the two edge-parity halves
    acc.x += __shfl_xor(acc.x, 32);
    acc.y += __shfl_xor(acc.y, 32);
    acc.z += __shfl_xor(acc.z, 32);
    acc.w += __shfl_xor(acc.w, 32);
    den   += __shfl_xor(den, 32);

    if (h == 0) {
        float4 r = {0.f, 0.f, 0.f, 0.f};
        if (s1 > s0) {
            const float inv = 1.f / den;
            r.x = acc.x * inv; r.y = acc.y * inv;
            r.z = acc.z * inv; r.w = acc.w * inv;
        }
        ((float4*)(context + (size_t)f * DD))[l] = r;
    }
}

// Stage 1: partial[sy][b][d] = sum over this slice's k of values[b][k]*context[k][d]
// grid: (4 b-tiles of 64, NSPLIT k-slices). Register tile 8b x 4d. NO atomics.
__global__ __launch_bounds__(256) void out_gemm_partial(
    const float* __restrict__ values, const float* __restrict__ context,
    float* __restrict__ partial)
{
    __shared__ float vl[64][64];    // 16KB values tile [b][k]
    __shared__ float xl[64][128];   // 32KB context tile [k][d]

    const int b0 = blockIdx.x * 64;
    const int sy = blockIdx.y;
    // k-range of this slice, in float4 units (5000 total; NF = 5000*4 exactly)
    const int s0_4 = (sy * 5000) >> 7;        // /NSPLIT
    const int s1_4 = ((sy + 1) * 5000) >> 7;
    const int t  = threadIdx.x;
    const int dg = t & 31;          // d = dg*4 .. dg*4+3
    const int bg = t >> 5;          // b = b0 + bg*8 .. +7

    float4 acc[8];
#pragma unroll
    for (int i = 0; i < 8; ++i) acc[i] = (float4){0.f, 0.f, 0.f, 0.f};

    for (int t4 = s0_4; t4 < s1_4; t4 += 16) {
        const int kt4 = min(16, s1_4 - t4);   // float4 units in this tile
        __syncthreads();
        // stage values tile: slots (bb, kq), kq in f4 units, coalesced along k
#pragma unroll
        for (int it = 0; it < 4; ++it) {
            int idx = t + it * 256;          // 0..1023
            int bb = idx >> 4;               // 0..63
            int kq = idx & 15;               // 0..15
            if (kq < kt4)
                *(float4*)&vl[bb][kq * 4] =
                    *(const float4*)&values[(size_t)(b0 + bb) * NF + (t4 + kq) * 4];
        }
        // stage context tile: rows kk (k within tile), coalesced along d
#pragma unroll
        for (int it = 0; it < 8; ++it) {
            int idx = t + it * 256;          // 0..2047
            int kk = idx >> 5;               // 0..63
            int c4 = (idx & 31) * 4;
            if (kk < kt4 * 4)
                *(float4*)&xl[kk][c4] =
                    *(const float4*)&context[(size_t)(t4 * 4 + kk) * DD + c4];
        }
        __syncthreads();

        for (int k4 = 0; k4 < kt4; ++k4) {
            const float4 xv0 = *(const float4*)&xl[k4 * 4 + 0][dg * 4];
            const float4 xv1 = *(const float4*)&xl[k4 * 4 + 1][dg * 4];
            const float4 xv2 = *(const float4*)&xl[k4 * 4 + 2][dg * 4];
            const float4 xv3 = *(const float4*)&xl[k4 * 4 + 3][dg * 4];
#pragma unroll
            for (int i = 0; i < 8; ++i) {
                const float4 vv = *(const float4*)&vl[bg * 8 + i][k4 * 4];
                acc[i].x = fmaf(vv.x, xv0.x, acc[i].x);
                acc[i].y = fmaf(vv.x, xv0.y, acc[i].y);
                acc[i].z = fmaf(vv.x, xv0.z, acc[i].z);
                acc[i].w = fmaf(vv.x, xv0.w, acc[i].w);
                acc[i].x = fmaf(vv.y, xv1.x, acc[i].x);
                acc[i].y = fmaf(vv.y, xv1.y, acc[i].y);
                acc[i].z = fmaf(vv.y, xv1.z, acc[i].z);
                acc[i].w = fmaf(vv.y, xv1.w, acc[i].w);
                acc[i].x = fmaf(vv.z, xv2.x, acc[i].x);
                acc[i].y = fmaf(vv.z, xv2.y, acc[i].y);
                acc[i].z = fmaf(vv.z, xv2.z, acc[i].z);
                acc[i].w = fmaf(vv.z, xv2.w, acc[i].w);
                acc[i].x = fmaf(vv.w, xv3.x, acc[i].x);
                acc[i].y = fmaf(vv.w, xv3.y, acc[i].y);
                acc[i].z = fmaf(vv.w, xv3.z, acc[i].z);
                acc[i].w = fmaf(vv.w, xv3.w, acc[i].w);
            }
        }
    }

    // private partial store — plain coalesced float4 stores, no contention
    float* pbase = partial + (size_t)sy * (NB * DD);
#pragma unroll
    for (int i = 0; i < 8; ++i)
        *(float4*)&pbase[(size_t)(b0 + bg * 8 + i) * DD + dg * 4] = acc[i];
}

// Stage 2: out[idx] = sum_s partial[s][idx]. One thread per output, no atomics.
// grid: 256 blocks x 128 threads = 32768 threads (uses all CUs).
__global__ __launch_bounds__(128) void out_reduce_kernel(
    const float* __restrict__ partial, float* __restrict__ out)
{
    const int idx = blockIdx.x * 128 + threadIdx.x;
    float s = 0.f;
#pragma unroll 8
    for (int p = 0; p < NSPLIT; ++p)
        s += partial[(size_t)p * (NB * DD) + idx];
    out[idx] = s;
}

// ---------------- launch ----------------

extern "C" void kernel_launch(void* const* d_in, const int* in_sizes, int n_in,
                              void* d_out, int out_size, void* d_ws, size_t ws_size,
                              hipStream_t stream) {
    const float* values   = (const float*)d_in[0];
    const float* feat_emb = (const float*)d_in[1];
    const float* hid_emb  = (const float*)d_in[2];
    const float* w_kernel = (const float*)d_in[3];
    const float* w_bias   = (const float*)d_in[4];
    const float* u_kernel = (const float*)d_in[5];
    const float* corr     = (const float*)d_in[6];
    const void*  cp_raw   = d_in[7];
    const void*  fci_raw  = d_in[8];
    float* out = (float*)d_out;

    char* ws = (char*)d_ws;
    size_t off = 0;
    auto alloc = [&](size_t bytes) {
        size_t cur = off;
        off += (bytes + 511) & ~size_t(511);
        return cur;
    };
    int*   flag    = (int*)  (ws + alloc(4));
    int*   cp32    = (int*)  (ws + alloc(sizeof(int) * NE));
    int*   fci32   = (int*)  (ws + alloc(sizeof(int) * NE));
    int*   offs    = (int*)  (ws + alloc(sizeof(int) * (NF + 1)));
    float* P1      = (float*)(ws + alloc(sizeof(float) * (size_t)NF * AA));
    float* P2      = (float*)(ws + alloc(sizeof(float) * (size_t)NALL * AA));
    float* context = (float*)(ws + alloc(sizeof(float) * (size_t)NF * DD));
    float* partial = (float*)(ws + alloc(sizeof(float) * (size_t)NSPLIT * NB * DD));

    // 1. dtype probe + index conversion
    probe_kernel<<<1, 64, 0, stream>>>((const unsigned int*)fci_raw, flag);
    convert_kernel<<<(NE + 255) / 256, 256, 0, stream>>>(cp_raw, fci_raw, cp32, fci32, flag);

    // 2. projections P1 / P2
    proj_kernel<<<NALL / 32 + NF / 32, 256, 0, stream>>>(feat_emb, hid_emb, w_kernel,
                                                         w_bias, P1, P2);

    // 3. segment offsets
    offsets_kernel<<<(NF + 1 + 255) / 256, 256, 0, stream>>>(cp32, offs);

    // 4. fused score + segment softmax + weighted aggregation -> context
    fused_agg_kernel<<<(NF + 3) / 4, 256, 0, stream>>>(feat_emb, hid_emb, P1, P2,
                                                       u_kernel, corr, offs, fci32,
                                                       context);

    // 5. out = values @ context  (atomic-free two-stage split-K)
    dim3 ggrid(NB / 64, NSPLIT);
    out_gemm_partial<<<ggrid, 256, 0, stream>>>(values, context, partial);
    out_reduce_kernel<<<(NB * DD) / 128, 128, 0, stream>>>(partial, out);
}

// Round 7
// 252.661 us; speedup vs baseline: 1.5249x; 1.0046x over previous
//
#include <hip/hip_runtime.h>
#include <hip/hip_bf16.h>

#define NF 20000
#define NH 40000
#define NALL 60000
#define NE 640000
#define DD 128
#define AA 64
#define NB 256
#define NSPLIT 128   // out_gemm split-K slices (atomic-free two-stage)

// ---------------- helpers ----------------

__device__ __forceinline__ float fast_rcp(float x) {
#if __has_builtin(__builtin_amdgcn_rcpf)
    return __builtin_amdgcn_rcpf(x);
#else
    return 1.f / x;
#endif
}

// tanh(x) = 1 - 2/(exp(2x)+1); exact at +-inf via rcp(inf)=0
__device__ __forceinline__ float tanh_fast(float x) {
    float e = __expf(2.f * x);
    return 1.f - 2.f * fast_rcp(e + 1.f);
}

// ---------------- kernels ----------------

// Detect whether index arrays are int64 (high dwords all zero) or int32.
__global__ void probe_kernel(const unsigned int* __restrict__ fci_raw,
                             int* __restrict__ flag) {
    unsigned int v = fci_raw[threadIdx.x * 2 + 1];
    unsigned long long any = __ballot(v != 0);
    if (threadIdx.x == 0) flag[0] = (any == 0ull) ? 1 : 0;  // 1 => int64
}

__global__ void convert_kernel(const void* __restrict__ cp_raw,
                               const void* __restrict__ fci_raw,
                               int* __restrict__ cp32, int* __restrict__ fci32,
                               const int* __restrict__ flag) {
    int e = blockIdx.x * 256 + threadIdx.x;
    if (e >= NE) return;
    if (flag[0]) {
        cp32[e]  = (int)((const long long*)cp_raw)[e];
        fci32[e] = (int)((const long long*)fci_raw)[e];
    } else {
        cp32[e]  = ((const int*)cp_raw)[e];
        fci32[e] = ((const int*)fci_raw)[e];
    }
}

// offs[f] = lower_bound(cp32, f) for f in [0, NF]
__global__ void offsets_kernel(const int* __restrict__ cp32, int* __restrict__ offs) {
    int f = blockIdx.x * 256 + threadIdx.x;
    if (f > NF) return;
    int lo = 0, hi = NE;
    while (lo < hi) {
        int mid = (lo + hi) >> 1;
        if (cp32[mid] < f) lo = mid + 1; else hi = mid;
    }
    offs[f] = lo;
}

// P2[i][a] = all_emb[i] @ W2   (blocks [0, NALL/32))
// P1[f][a] = feat_emb[f] @ W1 + bias   (blocks [NALL/32, NALL/32+NF/32))
__global__ __launch_bounds__(256) void proj_kernel(
    const float* __restrict__ feat_emb, const float* __restrict__ hid_emb,
    const float* __restrict__ w_kernel, const float* __restrict__ w_bias,
    float* __restrict__ P1, float* __restrict__ P2)
{
    __shared__ float Wl[128 * 64];      // 32KB: relevant half of w_kernel
    __shared__ float embl[32][128];     // 16KB: 32 embedding rows

    const int blk  = blockIdx.x;
    const bool isP2 = blk < (NALL / 32);
    const int row0 = isP2 ? blk * 32 : (blk - NALL / 32) * 32;
    const int t = threadIdx.x;
    const int kbase = isP2 ? 128 * 64 : 0;   // W2 = rows [128,256), W1 = rows [0,128)

#pragma unroll
    for (int i = 0; i < 32; ++i) {
        int idx = t + i * 256;
        Wl[idx] = w_kernel[kbase + idx];
    }
#pragma unroll
    for (int i = 0; i < 16; ++i) {
        int idx = t + i * 256;
        int r = idx >> 7, c = idx & 127;
        int grow = row0 + r;
        const float* src;
        if (isP2)
            src = (grow < NF) ? (feat_emb + (size_t)grow * DD)
                              : (hid_emb + (size_t)(grow - NF) * DD);
        else
            src = feat_emb + (size_t)grow * DD;
        embl[r][c] = src[c];
    }
    __syncthreads();

    const int a  = t & 63;
    const int rg = t >> 6;   // wave id: rows rg*8 .. rg*8+7
    float acc[8];
#pragma unroll
    for (int j = 0; j < 8; ++j) acc[j] = 0.f;

    for (int k4 = 0; k4 < 32; ++k4) {
        const int k = k4 * 4;
        float w0 = Wl[(k + 0) * 64 + a];
        float w1 = Wl[(k + 1) * 64 + a];
        float w2 = Wl[(k + 2) * 64 + a];
        float w3 = Wl[(k + 3) * 64 + a];
#pragma unroll
        for (int j = 0; j < 8; ++j) {
            const float4 ev = *(const float4*)&embl[rg * 8 + j][k];
            acc[j] = fmaf(ev.x, w0, acc[j]);
            acc[j] = fmaf(ev.y, w1, acc[j]);
            acc[j] = fmaf(ev.z, w2, acc[j]);
            acc[j] = fmaf(ev.w, w3, acc[j]);
        }
    }

    if (isP2) {
#pragma unroll
        for (int j = 0; j < 8; ++j)
            P2[(size_t)(row0 + rg * 8 + j) * AA + a] = acc[j];
    } else {
        float b = w_bias[a];
#pragma unroll
        for (int j = 0; j < 8; ++j)
            P1[(size_t)(row0 + rg * 8 + j) * AA + a] = acc[j] + b;
    }
}

// Fused score + segment-softmax + aggregation.
// One wave per feature; 4 edges in flight per wave step: q = lane>>4 is the
// edge slot, l = lane&15 the dim lane. P2 row = float4/lane (256B), emb row =
// 2x float4/lane. Score reduce = 4 shfl_xor steps within 16 lanes, amortized
// over 4 edges. Depth-1 prefetch => 8 edges in flight. Branchless masking:
// invalid slots carry cr=0 and reuse a valid index (legal, cache-hot address).
__global__ __launch_bounds__(256) void fused_agg_kernel(
    const float* __restrict__ feat_emb, const float* __restrict__ hid_emb,
    const float* __restrict__ P1, const float* __restrict__ P2,
    const float* __restrict__ u_kernel, const float* __restrict__ corr,
    const int* __restrict__ offs, const int* __restrict__ fci32,
    float* __restrict__ context)
{
    const int wave = threadIdx.x >> 6;          // 0..3
    const int lane = threadIdx.x & 63;
    const int q = lane >> 4;                    // edge slot 0..3
    const int l = lane & 15;                    // dim lane
    const int f = blockIdx.x * 4 + wave;
    if (f >= NF) return;

    const int s0 = offs[f], s1 = offs[f + 1];

    const float4 p1v = ((const float4*)(P1 + (size_t)f * AA))[l];
    const float4 uv  = ((const float4*)u_kernel)[l];

    float4 acc0 = {0.f, 0.f, 0.f, 0.f};
    float4 acc1 = {0.f, 0.f, 0.f, 0.f};
    float den = 0.f;

    for (int cb = s0; cb < s1; cb += 32) {
        const int clen = min(32, s1 - cb);
        // cooperative coalesced chunk load of indices / corrective terms
        int   idxr = 0;
        float crr  = 0.f;
        if (lane < clen) {
            idxr = fci32[cb + lane];
            crr  = corr[cb + lane];
        }
        const int nit = (clen + 3) >> 2;        // slot q handles e = cb+4t+q

        // prologue: stage A = edge (t=0, slot q). Lanes with q>=clen read
        // lane q's zero-init idxr (row 0 - valid address) and get crA=0.
        int   iA  = __shfl(idxr, q);
        float crA = (q < clen) ? __shfl(crr, q) : 0.f;
        float4 p2A = ((const float4*)(P2 + (size_t)iA * AA))[l];
        const float* srcA = (iA < NF) ? feat_emb + (size_t)iA * DD
                                      : hid_emb + (size_t)(iA - NF) * DD;
        float4 emA0 = ((const float4*)srcA)[l];
        float4 emA1 = ((const float4*)srcA)[l + 16];

        for (int t = 0; t < nit; ++t) {
            // prefetch stage B = edge (t+1, slot q); branchless mask via cr=0
            const int jn = 4 * (t + 1) + q;
            int   iB  = __shfl(idxr, jn & 31);
            float crB = __shfl(crr, jn & 31);
            if (jn >= clen) { iB = iA; crB = 0.f; }
            float4 p2B = ((const float4*)(P2 + (size_t)iB * AA))[l];
            const float* srcB = (iB < NF) ? feat_emb + (size_t)iB * DD
                                          : hid_emb + (size_t)(iB - NF) * DD;
            float4 emB0 = ((const float4*)srcB)[l];
            float4 emB1 = ((const float4*)srcB)[l + 16];

            // score for current 4 edges (A) while B's gathers are in flight
            float part;
            part = tanh_fast(p1v.x + p2A.x) * uv.x;
            part = fmaf(tanh_fast(p1v.y + p2A.y), uv.y, part);
            part = fmaf(tanh_fast(p1v.z + p2A.z), uv.z, part);
            part = fmaf(tanh_fast(p1v.w + p2A.w), uv.w, part);
            part += __shfl_xor(part, 1);
            part += __shfl_xor(part, 2);
            part += __shfl_xor(part, 4);
            part += __shfl_xor(part, 8);
            const float sc = __expf(part) * crA;

            acc0.x = fmaf(sc, emA0.x, acc0.x);
            acc0.y = fmaf(sc, emA0.y, acc0.y);
            acc0.z = fmaf(sc, emA0.z, acc0.z);
            acc0.w = fmaf(sc, emA0.w, acc0.w);
            acc1.x = fmaf(sc, emA1.x, acc1.x);
            acc1.y = fmaf(sc, emA1.y, acc1.y);
            acc1.z = fmaf(sc, emA1.z, acc1.z);
            acc1.w = fmaf(sc, emA1.w, acc1.w);
            den += sc;

            iA = iB; crA = crB; p2A = p2B; emA0 = emB0; emA1 = emB1;
        }
    }

    // combine the four edge slots (quarters): xor 16 then 32
    acc0.x += __shfl_xor(acc0.x, 16); acc0.x += __shfl_xor(acc0.x, 32);
    acc0.y += __shfl_xor(acc0.y, 16); acc0.y += __shfl_xor(acc0.y, 32);
    acc0.z += __shfl_xor(acc0.z, 16); acc0.z += __shfl_xor(acc0.z, 32);
    acc0.w += __shfl_xor(acc0.w, 16); acc0.w += __shfl_xor(acc0.w, 32);
    acc1.x += __shfl_xor(acc1.x, 16); acc1.x += __shfl_xor(acc1.x, 32);
    acc1.y += __shfl_xor(acc1.y, 16); acc1.y += __shfl_xor(acc1.y, 32);
    acc1.z += __shfl_xor(acc1.z, 16); acc1.z += __shfl_xor(acc1.z, 32);
    acc1.w += __shfl_xor(acc1.w, 16); acc1.w += __shfl_xor(acc1.w, 32);
    den += __shfl_xor(den, 16); den += __shfl_xor(den, 32);

    if (q == 0) {
        float4 r0 = {0.f, 0.f, 0.f, 0.f};
        float4 r1 = {0.f, 0.f, 0.f, 0.f};
        if (s1 > s0) {
            const float inv = 1.f / den;
            r0.x = acc0.x * inv; r0.y = acc0.y * inv;
            r0.z = acc0.z * inv; r0.w = acc0.w * inv;
            r1.x = acc1.x * inv; r1.y = acc1.y * inv;
            r1.z = acc1.z * inv; r1.w = acc1.w * inv;
        }
        ((float4*)(context + (size_t)f * DD))[l] = r0;
        ((float4*)(context + (size_t)f * DD))[l + 16] = r1;
    }
}

// Stage 1: partial[sy][b][d] = sum over this slice's k of values[b][k]*context[k][d]
// grid: (4 b-tiles of 64, NSPLIT k-slices). Register tile 8b x 4d. NO atomics.
__global__ __launch_bounds__(256) void out_gemm_partial(
    const float* __restrict__ values, const float* __restrict__ context,
    float* __restrict__ partial)
{
    __shared__ float vl[64][64];    // 16KB values tile [b][k]
    __shared__ float xl[64][128];   // 32KB context tile [k][d]

    const int b0 = blockIdx.x * 64;
    const int sy = blockIdx.y;
    // k-range of this slice, in float4 units (5000 total; NF = 5000*4 exactly)
    const int s0_4 = (sy * 5000) >> 7;        // /NSPLIT
    const int s1_4 = ((sy + 1) * 5000) >> 7;
    const int t  = threadIdx.x;
    const int dg = t & 31;          // d = dg*4 .. dg*4+3
    const int bg = t >> 5;          // b = b0 + bg*8 .. +7

    float4 acc[8];
#pragma unroll
    for (int i = 0; i < 8; ++i) acc[i] = (float4){0.f, 0.f, 0.f, 0.f};

    for (int t4 = s0_4; t4 < s1_4; t4 += 16) {
        const int kt4 = min(16, s1_4 - t4);   // float4 units in this tile
        __syncthreads();
        // stage values tile: slots (bb, kq), kq in f4 units, coalesced along k
#pragma unroll
        for (int it = 0; it < 4; ++it) {
            int idx = t + it * 256;          // 0..1023
            int bb = idx >> 4;               // 0..63
            int kq = idx & 15;               // 0..15
            if (kq < kt4)
                *(float4*)&vl[bb][kq * 4] =
                    *(const float4*)&values[(size_t)(b0 + bb) * NF + (t4 + kq) * 4];
        }
        // stage context tile: rows kk (k within tile), coalesced along d
#pragma unroll
        for (int it = 0; it < 8; ++it) {
            int idx = t + it * 256;          // 0..2047
            int kk = idx >> 5;               // 0..63
            int c4 = (idx & 31) * 4;
            if (kk < kt4 * 4)
                *(float4*)&xl[kk][c4] =
                    *(const float4*)&context[(size_t)(t4 * 4 + kk) * DD + c4];
        }
        __syncthreads();

        for (int k4 = 0; k4 < kt4; ++k4) {
            const float4 xv0 = *(const float4*)&xl[k4 * 4 + 0][dg * 4];
            const float4 xv1 = *(const float4*)&xl[k4 * 4 + 1][dg * 4];
            const float4 xv2 = *(const float4*)&xl[k4 * 4 + 2][dg * 4];
            const float4 xv3 = *(const float4*)&xl[k4 * 4 + 3][dg * 4];
#pragma unroll
            for (int i = 0; i < 8; ++i) {
                const float4 vv = *(const float4*)&vl[bg * 8 + i][k4 * 4];
                acc[i].x = fmaf(vv.x, xv0.x, acc[i].x);
                acc[i].y = fmaf(vv.x, xv0.y, acc[i].y);
                acc[i].z = fmaf(vv.x, xv0.z, acc[i].z);
                acc[i].w = fmaf(vv.x, xv0.w, acc[i].w);
                acc[i].x = fmaf(vv.y, xv1.x, acc[i].x);
                acc[i].y = fmaf(vv.y, xv1.y, acc[i].y);
                acc[i].z = fmaf(vv.y, xv1.z, acc[i].z);
                acc[i].w = fmaf(vv.y, xv1.w, acc[i].w);
                acc[i].x = fmaf(vv.z, xv2.x, acc[i].x);
                acc[i].y = fmaf(vv.z, xv2.y, acc[i].y);
                acc[i].z = fmaf(vv.z, xv2.z, acc[i].z);
                acc[i].w = fmaf(vv.z, xv2.w, acc[i].w);
                acc[i].x = fmaf(vv.w, xv3.x, acc[i].x);
                acc[i].y = fmaf(vv.w, xv3.y, acc[i].y);
                acc[i].z = fmaf(vv.w, xv3.z, acc[i].z);
                acc[i].w = fmaf(vv.w, xv3.w, acc[i].w);
            }
        }
    }

    // private partial store — plain coalesced float4 stores, no contention
    float* pbase = partial + (size_t)sy * (NB * DD);
#pragma unroll
    for (int i = 0; i < 8; ++i)
        *(float4*)&pbase[(size_t)(b0 + bg * 8 + i) * DD + dg * 4] = acc[i];
}

// Stage 2: out[idx] = sum_s partial[s][idx]. One thread per output, no atomics.
// grid: 256 blocks x 128 threads = 32768 threads (uses all CUs).
__global__ __launch_bounds__(128) void out_reduce_kernel(
    const float* __restrict__ partial, float* __restrict__ out)
{
    const int idx = blockIdx.x * 128 + threadIdx.x;
    float s = 0.f;
#pragma unroll 8
    for (int p = 0; p < NSPLIT; ++p)
        s += partial[(size_t)p * (NB * DD) + idx];
    out[idx] = s;
}

// ---------------- launch ----------------

extern "C" void kernel_launch(void* const* d_in, const int* in_sizes, int n_in,
                              void* d_out, int out_size, void* d_ws, size_t ws_size,
                              hipStream_t stream) {
    const float* values   = (const float*)d_in[0];
    const float* feat_emb = (const float*)d_in[1];
    const float* hid_emb  = (const float*)d_in[2];
    const float* w_kernel = (const float*)d_in[3];
    const float* w_bias   = (const float*)d_in[4];
    const float* u_kernel = (const float*)d_in[5];
    const float* corr     = (const float*)d_in[6];
    const void*  cp_raw   = d_in[7];
    const void*  fci_raw  = d_in[8];
    float* out = (float*)d_out;

    char* ws = (char*)d_ws;
    size_t off = 0;
    auto alloc = [&](size_t bytes) {
        size_t cur = off;
        off += (bytes + 511) & ~size_t(511);
        return cur;
    };
    int*   flag    = (int*)  (ws + alloc(4));
    int*   cp32    = (int*)  (ws + alloc(sizeof(int) * NE));
    int*   fci32   = (int*)  (ws + alloc(sizeof(int) * NE));
    int*   offs    = (int*)  (ws + alloc(sizeof(int) * (NF + 1)));
    float* P1      = (float*)(ws + alloc(sizeof(float) * (size_t)NF * AA));
    float* P2      = (float*)(ws + alloc(sizeof(float) * (size_t)NALL * AA));
    float* context = (float*)(ws + alloc(sizeof(float) * (size_t)NF * DD));
    float* partial = (float*)(ws + alloc(sizeof(float) * (size_t)NSPLIT * NB * DD));

    // 1. dtype probe + index conversion
    probe_kernel<<<1, 64, 0, stream>>>((const unsigned int*)fci_raw, flag);
    convert_kernel<<<(NE + 255) / 256, 256, 0, stream>>>(cp_raw, fci_raw, cp32, fci32, flag);

    // 2. projections P1 / P2
    proj_kernel<<<NALL / 32 + NF / 32, 256, 0, stream>>>(feat_emb, hid_emb, w_kernel,
                                                         w_bias, P1, P2);

    // 3. segment offsets
    offsets_kernel<<<(NF + 1 + 255) / 256, 256, 0, stream>>>(cp32, offs);

    // 4. fused score + segment softmax + weighted aggregation -> context
    fused_agg_kernel<<<(NF + 3) / 4, 256, 0, stream>>>(feat_emb, hid_emb, P1, P2,
                                                       u_kernel, corr, offs, fci32,
                                                       context);

    // 5. out = values @ context  (atomic-free two-stage split-K)
    dim3 ggrid(NB / 64, NSPLIT);
    out_gemm_partial<<<ggrid, 256, 0, stream>>>(values, context, partial);
    out_reduce_kernel<<<(NB * DD) / 128, 128, 0, stream>>>(partial, out);
}

// Round 8
// 222.734 us; speedup vs baseline: 1.7298x; 1.1344x over previous
//
#include <hip/hip_runtime.h>
#include <hip/hip_bf16.h>
#include <hip/hip_fp16.h>

#define NF 20000
#define NH 40000
#define NALL 60000
#define NE 640000
#define DD 128
#define AA 64
#define NB 256
#define NSPLIT 128   // out_gemm split-K slices (atomic-free two-stage)

// ---------------- helpers ----------------

__device__ __forceinline__ float fast_rcp(float x) {
#if __has_builtin(__builtin_amdgcn_rcpf)
    return __builtin_amdgcn_rcpf(x);
#else
    return 1.f / x;
#endif
}

// tanh(x) = 1 - 2/(exp(2x)+1); exact at +-inf via rcp(inf)=0
__device__ __forceinline__ float tanh_fast(float x) {
    float e = __expf(2.f * x);
    return 1.f - 2.f * fast_rcp(e + 1.f);
}

// ---------------- kernels ----------------

// Detect whether index arrays are int64 (high dwords all zero) or int32.
__global__ void probe_kernel(const unsigned int* __restrict__ fci_raw,
                             int* __restrict__ flag) {
    unsigned int v = fci_raw[threadIdx.x * 2 + 1];
    unsigned long long any = __ballot(v != 0);
    if (threadIdx.x == 0) flag[0] = (any == 0ull) ? 1 : 0;  // 1 => int64
}

__global__ void convert_kernel(const void* __restrict__ cp_raw,
                               const void* __restrict__ fci_raw,
                               int* __restrict__ cp32, int* __restrict__ fci32,
                               const int* __restrict__ flag) {
    int e = blockIdx.x * 256 + threadIdx.x;
    if (e >= NE) return;
    if (flag[0]) {
        cp32[e]  = (int)((const long long*)cp_raw)[e];
        fci32[e] = (int)((const long long*)fci_raw)[e];
    } else {
        cp32[e]  = ((const int*)cp_raw)[e];
        fci32[e] = ((const int*)fci_raw)[e];
    }
}

// offs[f] = lower_bound(cp32, f) for f in [0, NF]
__global__ void offsets_kernel(const int* __restrict__ cp32, int* __restrict__ offs) {
    int f = blockIdx.x * 256 + threadIdx.x;
    if (f > NF) return;
    int lo = 0, hi = NE;
    while (lo < hi) {
        int mid = (lo + hi) >> 1;
        if (cp32[mid] < f) lo = mid + 1; else hi = mid;
    }
    offs[f] = lo;
}

// P2h[i][a] = fp16( all_emb[i] @ W2 )       (blocks [0, NALL/32))
//   + embH[i][:] = fp16(all_emb[i][:])      (same blocks, staged rows reused)
// P1[f][a]  = fp32( feat_emb[f] @ W1 + b )  (blocks [NALL/32, NALL/32+NF/32))
__global__ __launch_bounds__(256) void proj_kernel(
    const float* __restrict__ feat_emb, const float* __restrict__ hid_emb,
    const float* __restrict__ w_kernel, const float* __restrict__ w_bias,
    float* __restrict__ P1, __half* __restrict__ P2h, __half* __restrict__ embH)
{
    __shared__ float Wl[128 * 64];      // 32KB: relevant half of w_kernel
    __shared__ float embl[32][128];     // 16KB: 32 embedding rows

    const int blk  = blockIdx.x;
    const bool isP2 = blk < (NALL / 32);
    const int row0 = isP2 ? blk * 32 : (blk - NALL / 32) * 32;
    const int t = threadIdx.x;
    const int kbase = isP2 ? 128 * 64 : 0;   // W2 = rows [128,256), W1 = rows [0,128)

#pragma unroll
    for (int i = 0; i < 32; ++i) {
        int idx = t + i * 256;
        Wl[idx] = w_kernel[kbase + idx];
    }
#pragma unroll
    for (int i = 0; i < 16; ++i) {
        int idx = t + i * 256;
        int r = idx >> 7, c = idx & 127;
        int grow = row0 + r;
        const float* src;
        if (isP2)
            src = (grow < NF) ? (feat_emb + (size_t)grow * DD)
                              : (hid_emb + (size_t)(grow - NF) * DD);
        else
            src = feat_emb + (size_t)grow * DD;
        embl[r][c] = src[c];
    }
    __syncthreads();

    // emit the fp16 combined embedding table from the staged rows
    if (isP2) {
#pragma unroll
        for (int i = 0; i < 8; ++i) {
            int idx = t + i * 256;          // 0..2047 half2 slots (32 rows x 64)
            int r = idx >> 6, c2 = idx & 63;
            float2 v = *(const float2*)&embl[r][c2 * 2];
            ((__half2*)embH)[(size_t)(row0 + r) * 64 + c2] = __float22half2_rn(v);
        }
    }

    const int a  = t & 63;
    const int rg = t >> 6;   // wave id: rows rg*8 .. rg*8+7
    float acc[8];
#pragma unroll
    for (int j = 0; j < 8; ++j) acc[j] = 0.f;

    for (int k4 = 0; k4 < 32; ++k4) {
        const int k = k4 * 4;
        float w0 = Wl[(k + 0) * 64 + a];
        float w1 = Wl[(k + 1) * 64 + a];
        float w2 = Wl[(k + 2) * 64 + a];
        float w3 = Wl[(k + 3) * 64 + a];
#pragma unroll
        for (int j = 0; j < 8; ++j) {
            const float4 ev = *(const float4*)&embl[rg * 8 + j][k];
            acc[j] = fmaf(ev.x, w0, acc[j]);
            acc[j] = fmaf(ev.y, w1, acc[j]);
            acc[j] = fmaf(ev.z, w2, acc[j]);
            acc[j] = fmaf(ev.w, w3, acc[j]);
        }
    }

    if (isP2) {
#pragma unroll
        for (int j = 0; j < 8; ++j)
            P2h[(size_t)(row0 + rg * 8 + j) * AA + a] = __float2half(acc[j]);
    } else {
        float b = w_bias[a];
#pragma unroll
        for (int j = 0; j < 8; ++j)
            P1[(size_t)(row0 + rg * 8 + j) * AA + a] = acc[j] + b;
    }
}

// Fused score + segment-softmax + aggregation.
// One wave per feature; 4 edges per step (q = lane>>4 edge slot, l = lane&15
// dim lane). fp16 gather tables: P2h row = uint2/lane (128B), embH row =
// uint4/lane (256B, single dwordx4). Depth-1 prefetch => 8 edges in flight.
// Branchless masking via cr=0; fp32 arithmetic throughout.
__global__ __launch_bounds__(256) void fused_agg_kernel(
    const __half* __restrict__ embH, const float* __restrict__ P1,
    const __half* __restrict__ P2h, const float* __restrict__ u_kernel,
    const float* __restrict__ corr, const int* __restrict__ offs,
    const int* __restrict__ fci32, float* __restrict__ context)
{
    const int wave = threadIdx.x >> 6;          // 0..3
    const int lane = threadIdx.x & 63;
    const int q = lane >> 4;                    // edge slot 0..3
    const int l = lane & 15;                    // dim lane
    const int f = blockIdx.x * 4 + wave;
    if (f >= NF) return;

    const int s0 = offs[f], s1 = offs[f + 1];

    const float4 p1v = ((const float4*)(P1 + (size_t)f * AA))[l];
    const float4 uv  = ((const float4*)u_kernel)[l];

    float4 acc0 = {0.f, 0.f, 0.f, 0.f};
    float4 acc1 = {0.f, 0.f, 0.f, 0.f};
    float den = 0.f;

    for (int cb = s0; cb < s1; cb += 32) {
        const int clen = min(32, s1 - cb);
        // cooperative coalesced chunk load of indices / corrective terms
        int   idxr = 0;
        float crr  = 0.f;
        if (lane < clen) {
            idxr = fci32[cb + lane];
            crr  = corr[cb + lane];
        }
        const int nit = (clen + 3) >> 2;        // slot q handles e = cb+4t+q

        // prologue: stage A = edge (t=0, slot q). Lanes with q>=clen read
        // lane q's zero-init idxr (row 0 - valid address) and get crA=0.
        int   iA  = __shfl(idxr, q);
        float crA = (q < clen) ? __shfl(crr, q) : 0.f;
        uint2 p2A = ((const uint2*)(P2h + (size_t)iA * AA))[l];
        uint4 emA = ((const uint4*)(embH + (size_t)iA * DD))[l];

        for (int t = 0; t < nit; ++t) {
            // prefetch stage B = edge (t+1, slot q); branchless mask via cr=0
            const int jn = 4 * (t + 1) + q;
            int   iB  = __shfl(idxr, jn & 31);
            float crB = __shfl(crr, jn & 31);
            if (jn >= clen) { iB = iA; crB = 0.f; }
            uint2 p2B = ((const uint2*)(P2h + (size_t)iB * AA))[l];
            uint4 emB = ((const uint4*)(embH + (size_t)iB * DD))[l];

            // score for current 4 edges (A) while B's gathers are in flight
            const float2 pa = __half22float2(*(const __half2*)&p2A.x);
            const float2 pb = __half22float2(*(const __half2*)&p2A.y);
            float part;
            part = tanh_fast(p1v.x + pa.x) * uv.x;
            part = fmaf(tanh_fast(p1v.y + pa.y), uv.y, part);
            part = fmaf(tanh_fast(p1v.z + pb.x), uv.z, part);
            part = fmaf(tanh_fast(p1v.w + pb.y), uv.w, part);
            part += __shfl_xor(part, 1);
            part += __shfl_xor(part, 2);
            part += __shfl_xor(part, 4);
            part += __shfl_xor(part, 8);
            const float sc = __expf(part) * crA;

            const float2 e0 = __half22float2(*(const __half2*)&emA.x);
            const float2 e1 = __half22float2(*(const __half2*)&emA.y);
            const float2 e2 = __half22float2(*(const __half2*)&emA.z);
            const float2 e3 = __half22float2(*(const __half2*)&emA.w);
            acc0.x = fmaf(sc, e0.x, acc0.x);
            acc0.y = fmaf(sc, e0.y, acc0.y);
            acc0.z = fmaf(sc, e1.x, acc0.z);
            acc0.w = fmaf(sc, e1.y, acc0.w);
            acc1.x = fmaf(sc, e2.x, acc1.x);
            acc1.y = fmaf(sc, e2.y, acc1.y);
            acc1.z = fmaf(sc, e3.x, acc1.z);
            acc1.w = fmaf(sc, e3.y, acc1.w);
            den += sc;

            iA = iB; crA = crB; p2A = p2B; emA = emB;
        }
    }

    // combine the four edge slots (quarters): xor 16 then 32
    acc0.x += __shfl_xor(acc0.x, 16); acc0.x += __shfl_xor(acc0.x, 32);
    acc0.y += __shfl_xor(acc0.y, 16); acc0.y += __shfl_xor(acc0.y, 32);
    acc0.z += __shfl_xor(acc0.z, 16); acc0.z += __shfl_xor(acc0.z, 32);
    acc0.w += __shfl_xor(acc0.w, 16); acc0.w += __shfl_xor(acc0.w, 32);
    acc1.x += __shfl_xor(acc1.x, 16); acc1.x += __shfl_xor(acc1.x, 32);
    acc1.y += __shfl_xor(acc1.y, 16); acc1.y += __shfl_xor(acc1.y, 32);
    acc1.z += __shfl_xor(acc1.z, 16); acc1.z += __shfl_xor(acc1.z, 32);
    acc1.w += __shfl_xor(acc1.w, 16); acc1.w += __shfl_xor(acc1.w, 32);
    den += __shfl_xor(den, 16); den += __shfl_xor(den, 32);

    if (q == 0) {
        float4 r0 = {0.f, 0.f, 0.f, 0.f};
        float4 r1 = {0.f, 0.f, 0.f, 0.f};
        if (s1 > s0) {
            const float inv = 1.f / den;
            r0.x = acc0.x * inv; r0.y = acc0.y * inv;
            r0.z = acc0.z * inv; r0.w = acc0.w * inv;
            r1.x = acc1.x * inv; r1.y = acc1.y * inv;
            r1.z = acc1.z * inv; r1.w = acc1.w * inv;
        }
        // lane l holds d = 8l..8l+7
        ((float4*)(context + (size_t)f * DD))[2 * l]     = r0;
        ((float4*)(context + (size_t)f * DD))[2 * l + 1] = r1;
    }
}

// Stage 1: partial[sy][b][d] = sum over this slice's k of values[b][k]*context[k][d]
// grid: (4 b-tiles of 64, NSPLIT k-slices). Register tile 8b x 4d. NO atomics.
__global__ __launch_bounds__(256) void out_gemm_partial(
    const float* __restrict__ values, const float* __restrict__ context,
    float* __restrict__ partial)
{
    __shared__ float vl[64][64];    // 16KB values tile [b][k]
    __shared__ float xl[64][128];   // 32KB context tile [k][d]

    const int b0 = blockIdx.x * 64;
    const int sy = blockIdx.y;
    // k-range of this slice, in float4 units (5000 total; NF = 5000*4 exactly)
    const int s0_4 = (sy * 5000) >> 7;        // /NSPLIT
    const int s1_4 = ((sy + 1) * 5000) >> 7;
    const int t  = threadIdx.x;
    const int dg = t & 31;          // d = dg*4 .. dg*4+3
    const int bg = t >> 5;          // b = b0 + bg*8 .. +7

    float4 acc[8];
#pragma unroll
    for (int i = 0; i < 8; ++i) acc[i] = (float4){0.f, 0.f, 0.f, 0.f};

    for (int t4 = s0_4; t4 < s1_4; t4 += 16) {
        const int kt4 = min(16, s1_4 - t4);   // float4 units in this tile
        __syncthreads();
        // stage values tile: slots (bb, kq), kq in f4 units, coalesced along k
#pragma unroll
        for (int it = 0; it < 4; ++it) {
            int idx = t + it * 256;          // 0..1023
            int bb = idx >> 4;               // 0..63
            int kq = idx & 15;               // 0..15
            if (kq < kt4)
                *(float4*)&vl[bb][kq * 4] =
                    *(const float4*)&values[(size_t)(b0 + bb) * NF + (t4 + kq) * 4];
        }
        // stage context tile: rows kk (k within tile), coalesced along d
#pragma unroll
        for (int it = 0; it < 8; ++it) {
            int idx = t + it * 256;          // 0..2047
            int kk = idx >> 5;               // 0..63
            int c4 = (idx & 31) * 4;
            if (kk < kt4 * 4)
                *(float4*)&xl[kk][c4] =
                    *(const float4*)&context[(size_t)(t4 * 4 + kk) * DD + c4];
        }
        __syncthreads();

        for (int k4 = 0; k4 < kt4; ++k4) {
            const float4 xv0 = *(const float4*)&xl[k4 * 4 + 0][dg * 4];
            const float4 xv1 = *(const float4*)&xl[k4 * 4 + 1][dg * 4];
            const float4 xv2 = *(const float4*)&xl[k4 * 4 + 2][dg * 4];
            const float4 xv3 = *(const float4*)&xl[k4 * 4 + 3][dg * 4];
#pragma unroll
            for (int i = 0; i < 8; ++i) {
                const float4 vv = *(const float4*)&vl[bg * 8 + i][k4 * 4];
                acc[i].x = fmaf(vv.x, xv0.x, acc[i].x);
                acc[i].y = fmaf(vv.x, xv0.y, acc[i].y);
                acc[i].z = fmaf(vv.x, xv0.z, acc[i].z);
                acc[i].w = fmaf(vv.x, xv0.w, acc[i].w);
                acc[i].x = fmaf(vv.y, xv1.x, acc[i].x);
                acc[i].y = fmaf(vv.y, xv1.y, acc[i].y);
                acc[i].z = fmaf(vv.y, xv1.z, acc[i].z);
                acc[i].w = fmaf(vv.y, xv1.w, acc[i].w);
                acc[i].x = fmaf(vv.z, xv2.x, acc[i].x);
                acc[i].y = fmaf(vv.z, xv2.y, acc[i].y);
                acc[i].z = fmaf(vv.z, xv2.z, acc[i].z);
                acc[i].w = fmaf(vv.z, xv2.w, acc[i].w);
                acc[i].x = fmaf(vv.w, xv3.x, acc[i].x);
                acc[i].y = fmaf(vv.w, xv3.y, acc[i].y);
                acc[i].z = fmaf(vv.w, xv3.z, acc[i].z);
                acc[i].w = fmaf(vv.w, xv3.w, acc[i].w);
            }
        }
    }

    // private partial store — plain coalesced float4 stores, no contention
    float* pbase = partial + (size_t)sy * (NB * DD);
#pragma unroll
    for (int i = 0; i < 8; ++i)
        *(float4*)&pbase[(size_t)(b0 + bg * 8 + i) * DD + dg * 4] = acc[i];
}

// Stage 2: out[idx] = sum_s partial[s][idx]. One thread per output, no atomics.
// grid: 256 blocks x 128 threads = 32768 threads (uses all CUs).
__global__ __launch_bounds__(128) void out_reduce_kernel(
    const float* __restrict__ partial, float* __restrict__ out)
{
    const int idx = blockIdx.x * 128 + threadIdx.x;
    float s = 0.f;
#pragma unroll 8
    for (int p = 0; p < NSPLIT; ++p)
        s += partial[(size_t)p * (NB * DD) + idx];
    out[idx] = s;
}

// ---------------- launch ----------------

extern "C" void kernel_launch(void* const* d_in, const int* in_sizes, int n_in,
                              void* d_out, int out_size, void* d_ws, size_t ws_size,
                              hipStream_t stream) {
    const float* values   = (const float*)d_in[0];
    const float* feat_emb = (const float*)d_in[1];
    const float* hid_emb  = (const float*)d_in[2];
    const float* w_kernel = (const float*)d_in[3];
    const float* w_bias   = (const float*)d_in[4];
    const float* u_kernel = (const float*)d_in[5];
    const float* corr     = (const float*)d_in[6];
    const void*  cp_raw   = d_in[7];
    const void*  fci_raw  = d_in[8];
    float* out = (float*)d_out;

    char* ws = (char*)d_ws;
    size_t off = 0;
    auto alloc = [&](size_t bytes) {
        size_t cur = off;
        off += (bytes + 511) & ~size_t(511);
        return cur;
    };
    int*    flag    = (int*)   (ws + alloc(4));
    int*    cp32    = (int*)   (ws + alloc(sizeof(int) * NE));
    int*    fci32   = (int*)   (ws + alloc(sizeof(int) * NE));
    int*    offs    = (int*)   (ws + alloc(sizeof(int) * (NF + 1)));
    float*  P1      = (float*) (ws + alloc(sizeof(float) * (size_t)NF * AA));
    __half* P2h     = (__half*)(ws + alloc(sizeof(__half) * (size_t)NALL * AA));
    __half* embH    = (__half*)(ws + alloc(sizeof(__half) * (size_t)NALL * DD));
    float*  context = (float*) (ws + alloc(sizeof(float) * (size_t)NF * DD));
    float*  partial = (float*) (ws + alloc(sizeof(float) * (size_t)NSPLIT * NB * DD));

    // 1. dtype probe + index conversion
    probe_kernel<<<1, 64, 0, stream>>>((const unsigned int*)fci_raw, flag);
    convert_kernel<<<(NE + 255) / 256, 256, 0, stream>>>(cp_raw, fci_raw, cp32, fci32, flag);

    // 2. projections P1 / P2h + fp16 embedding table
    proj_kernel<<<NALL / 32 + NF / 32, 256, 0, stream>>>(feat_emb, hid_emb, w_kernel,
                                                         w_bias, P1, P2h, embH);

    // 3. segment offsets
    offsets_kernel<<<(NF + 1 + 255) / 256, 256, 0, stream>>>(cp32, offs);

    // 4. fused score + segment softmax + weighted aggregation -> context
    fused_agg_kernel<<<(NF + 3) / 4, 256, 0, stream>>>(embH, P1, P2h,
                                                       u_kernel, corr, offs, fci32,
                                                       context);

    // 5. out = values @ context  (atomic-free two-stage split-K)
    dim3 ggrid(NB / 64, NSPLIT);
    out_gemm_partial<<<ggrid, 256, 0, stream>>>(values, context, partial);
    out_reduce_kernel<<<(NB * DD) / 128, 128, 0, stream>>>(partial, out);
}

// Round 10
// 197.435 us; speedup vs baseline: 1.9515x; 1.1281x over previous
//
#include <hip/hip_runtime.h>
#include <hip/hip_bf16.h>
#include <hip/hip_fp16.h>

#define NF 20000
#define NH 40000
#define NALL 60000
#define NE 640000
#define DD 128
#define AA 64
#define NB 256
#define NSPLIT 128   // out_gemm split-K slices (atomic-free two-stage)

typedef __attribute__((ext_vector_type(8))) _Float16 f16x8;
typedef __attribute__((ext_vector_type(4))) float f32x4;

// ---------------- helpers ----------------

__device__ __forceinline__ float fast_rcp(float x) {
#if __has_builtin(__builtin_amdgcn_rcpf)
    return __builtin_amdgcn_rcpf(x);
#else
    return 1.f / x;
#endif
}

// tanh(x) = 1 - 2/(exp(2x)+1); exact at +-inf via rcp(inf)=0
__device__ __forceinline__ float tanh_fast(float x) {
    float e = __expf(2.f * x);
    return 1.f - 2.f * fast_rcp(e + 1.f);
}

// ---------------- kernels ----------------

// Detect whether index arrays are int64 (high dwords all zero) or int32.
__global__ void probe_kernel(const unsigned int* __restrict__ fci_raw,
                             int* __restrict__ flag) {
    unsigned int v = fci_raw[threadIdx.x * 2 + 1];
    unsigned long long any = __ballot(v != 0);
    if (threadIdx.x == 0) flag[0] = (any == 0ull) ? 1 : 0;  // 1 => int64
}

__global__ void convert_kernel(const void* __restrict__ cp_raw,
                               const void* __restrict__ fci_raw,
                               int* __restrict__ cp32, int* __restrict__ fci32,
                               const int* __restrict__ flag) {
    int e = blockIdx.x * 256 + threadIdx.x;
    if (e >= NE) return;
    if (flag[0]) {
        cp32[e]  = (int)((const long long*)cp_raw)[e];
        fci32[e] = (int)((const long long*)fci_raw)[e];
    } else {
        cp32[e]  = ((const int*)cp_raw)[e];
        fci32[e] = ((const int*)fci_raw)[e];
    }
}

// offs[f] = lower_bound(cp32, f) for f in [0, NF]
__global__ void offsets_kernel(const int* __restrict__ cp32, int* __restrict__ offs) {
    int f = blockIdx.x * 256 + threadIdx.x;
    if (f > NF) return;
    int lo = 0, hi = NE;
    while (lo < hi) {
        int mid = (lo + hi) >> 1;
        if (cp32[mid] < f) lo = mid + 1; else hi = mid;
    }
    offs[f] = lo;
}

// embH[i][:] = fp16(all_emb[i][:]) — thread handles 8 contiguous elements
__global__ __launch_bounds__(256) void prep_emb_kernel(
    const float* __restrict__ feat_emb, const float* __restrict__ hid_emb,
    __half* __restrict__ embH)
{
    const int tid = blockIdx.x * 256 + threadIdx.x;   // < NALL*DD/8 = 960000
    const int row = tid >> 4;                // 16 threads per 128-elem row
    const int c8 = (tid & 15) * 8;
    const float* src = (row < NF) ? feat_emb + (size_t)row * DD + c8
                                  : hid_emb + (size_t)(row - NF) * DD + c8;
    float4 v0 = ((const float4*)src)[0];
    float4 v1 = ((const float4*)src)[1];
    union { __half2 h2[4]; uint4 u; } cv;
    cv.h2[0] = __float22half2_rn({v0.x, v0.y});
    cv.h2[1] = __float22half2_rn({v0.z, v0.w});
    cv.h2[2] = __float22half2_rn({v1.x, v1.y});
    cv.h2[3] = __float22half2_rn({v1.z, v1.w});
    *(uint4*)(embH + (size_t)tid * 8) = cv.u;
}

// WtH[s][n][k] = fp16( w_kernel[s*128 + k][n] )  — transposed so MFMA B-frags
// (8 consecutive k per lane) are 16B-contiguous. s=0 -> W1, s=1 -> W2.
__global__ __launch_bounds__(256) void prep_w_kernel(
    const float* __restrict__ w_kernel, __half* __restrict__ WtH)
{
    const int t = blockIdx.x * 256 + threadIdx.x;  // < 2*64*128 = 16384
    const int s = t >> 13;
    const int n = (t >> 7) & 63;
    const int k = t & 127;
    WtH[t] = __float2half(w_kernel[(size_t)(s * 128 + k) * 64 + n]);
}

// Projection GEMM via MFMA (fp16 in, fp32 accum). One 16-row x 64-col tile per
// wave, K=128. Tiles 0..3749: P2h rows (all 60000 embH rows). Tiles
// 3750..4999: P1 rows (embH rows 0..19999 = feat) + bias, fp32 output.
// Fragment layouts (AMD lab-notes convention, C/D m89-verified):
//   A: row = lane&15, k = (lane>>4)*8 + j    (one b128 per frag)
//   B: col = lane&15, k = (lane>>4)*8 + j    (from transposed WtH)
//   C/D: col = lane&15, row = (lane>>4)*4 + reg
__global__ __launch_bounds__(256) void proj_mfma_kernel(
    const __half* __restrict__ embH, const __half* __restrict__ WtH,
    const float* __restrict__ w_bias, float* __restrict__ P1,
    __half* __restrict__ P2h)
{
    const int wave = threadIdx.x >> 6;
    const int lane = threadIdx.x & 63;
    const int ln = lane & 15;
    const int kh = lane >> 4;
    const int tile = blockIdx.x * 4 + wave;          // 0..4999
    const bool isP2 = tile < (NALL / 16);
    const int r0 = isP2 ? tile * 16 : (tile - NALL / 16) * 16;
    const __half* Wt = WtH + (isP2 ? (64 * 128) : 0);

    f16x8 bfrag[4][4];   // [n-tile][k-chunk], held in VGPRs for the whole tile
#pragma unroll
    for (int nt = 0; nt < 4; ++nt)
#pragma unroll
        for (int kc = 0; kc < 4; ++kc)
            bfrag[nt][kc] = *reinterpret_cast<const f16x8*>(
                Wt + (size_t)(nt * 16 + ln) * 128 + kc * 32 + kh * 8);

    f16x8 afrag[4];
#pragma unroll
    for (int kc = 0; kc < 4; ++kc)
        afrag[kc] = *reinterpret_cast<const f16x8*>(
            embH + (size_t)(r0 + ln) * DD + kc * 32 + kh * 8);

    f32x4 acc[4];
#pragma unroll
    for (int nt = 0; nt < 4; ++nt) {
        acc[nt] = (f32x4){0.f, 0.f, 0.f, 0.f};
#pragma unroll
        for (int kc = 0; kc < 4; ++kc)
            acc[nt] = __builtin_amdgcn_mfma_f32_16x16x32_f16(
                afrag[kc], bfrag[nt][kc], acc[nt], 0, 0, 0);
    }

    if (isP2) {
#pragma unroll
        for (int nt = 0; nt < 4; ++nt)
#pragma unroll
            for (int j = 0; j < 4; ++j)
                P2h[(size_t)(r0 + kh * 4 + j) * AA + nt * 16 + ln] =
                    __float2half(acc[nt][j]);
    } else {
#pragma unroll
        for (int nt = 0; nt < 4; ++nt) {
            const float b = w_bias[nt * 16 + ln];
#pragma unroll
            for (int j = 0; j < 4; ++j)
                P1[(size_t)(r0 + kh * 4 + j) * AA + nt * 16 + ln] =
                    acc[nt][j] + b;
        }
    }
}

// Fused score + segment-softmax + aggregation.
// One wave per feature; 4 edges per step (q = lane>>4 edge slot, l = lane&15
// dim lane). fp16 gather tables: P2h row = uint2/lane (128B), embH row =
// uint4/lane (256B, single dwordx4). Depth-1 prefetch => 8 edges in flight.
// Branchless masking via cr=0; fp32 arithmetic throughout.
__global__ __launch_bounds__(256) void fused_agg_kernel(
    const __half* __restrict__ embH, const float* __restrict__ P1,
    const __half* __restrict__ P2h, const float* __restrict__ u_kernel,
    const float* __restrict__ corr, const int* __restrict__ offs,
    const int* __restrict__ fci32, float* __restrict__ context)
{
    const int wave = threadIdx.x >> 6;          // 0..3
    const int lane = threadIdx.x & 63;
    const int q = lane >> 4;                    // edge slot 0..3
    const int l = lane & 15;                    // dim lane
    const int f = blockIdx.x * 4 + wave;
    if (f >= NF) return;

    const int s0 = offs[f], s1 = offs[f + 1];

    const float4 p1v = ((const float4*)(P1 + (size_t)f * AA))[l];
    const float4 uv  = ((const float4*)u_kernel)[l];

    float4 acc0 = {0.f, 0.f, 0.f, 0.f};
    float4 acc1 = {0.f, 0.f, 0.f, 0.f};
    float den = 0.f;

    for (int cb = s0; cb < s1; cb += 32) {
        const int clen = min(32, s1 - cb);
        // cooperative coalesced chunk load of indices / corrective terms
        int   idxr = 0;
        float crr  = 0.f;
        if (lane < clen) {
            idxr = fci32[cb + lane];
            crr  = corr[cb + lane];
        }
        const int nit = (clen + 3) >> 2;        // slot q handles e = cb+4t+q

        // prologue: stage A = edge (t=0, slot q). Lanes with q>=clen read
        // lane q's zero-init idxr (row 0 - valid address) and get crA=0.
        int   iA  = __shfl(idxr, q);
        float crA = (q < clen) ? __shfl(crr, q) : 0.f;
        uint2 p2A = ((const uint2*)(P2h + (size_t)iA * AA))[l];
        uint4 emA = ((const uint4*)(embH + (size_t)iA * DD))[l];

        for (int t = 0; t < nit; ++t) {
            // prefetch stage B = edge (t+1, slot q); branchless mask via cr=0
            const int jn = 4 * (t + 1) + q;
            int   iB  = __shfl(idxr, jn & 31);
            float crB = __shfl(crr, jn & 31);
            if (jn >= clen) { iB = iA; crB = 0.f; }
            uint2 p2B = ((const uint2*)(P2h + (size_t)iB * AA))[l];
            uint4 emB = ((const uint4*)(embH + (size_t)iB * DD))[l];

            // score for current 4 edges (A) while B's gathers are in flight
            const float2 pa = __half22float2(*(const __half2*)&p2A.x);
            const float2 pb = __half22float2(*(const __half2*)&p2A.y);
            float part;
            part = tanh_fast(p1v.x + pa.x) * uv.x;
            part = fmaf(tanh_fast(p1v.y + pa.y), uv.y, part);
            part = fmaf(tanh_fast(p1v.z + pb.x), uv.z, part);
            part = fmaf(tanh_fast(p1v.w + pb.y), uv.w, part);
            part += __shfl_xor(part, 1);
            part += __shfl_xor(part, 2);
            part += __shfl_xor(part, 4);
            part += __shfl_xor(part, 8);
            const float sc = __expf(part) * crA;

            const float2 e0 = __half22float2(*(const __half2*)&emA.x);
            const float2 e1 = __half22float2(*(const __half2*)&emA.y);
            const float2 e2 = __half22float2(*(const __half2*)&emA.z);
            const float2 e3 = __half22float2(*(const __half2*)&emA.w);
            acc0.x = fmaf(sc, e0.x, acc0.x);
            acc0.y = fmaf(sc, e0.y, acc0.y);
            acc0.z = fmaf(sc, e1.x, acc0.z);
            acc0.w = fmaf(sc, e1.y, acc0.w);
            acc1.x = fmaf(sc, e2.x, acc1.x);
            acc1.y = fmaf(sc, e2.y, acc1.y);
            acc1.z = fmaf(sc, e3.x, acc1.z);
            acc1.w = fmaf(sc, e3.y, acc1.w);
            den += sc;

            iA = iB; crA = crB; p2A = p2B; emA = emB;
        }
    }

    // combine the four edge slots (quarters): xor 16 then 32
    acc0.x += __shfl_xor(acc0.x, 16); acc0.x += __shfl_xor(acc0.x, 32);
    acc0.y += __shfl_xor(acc0.y, 16); acc0.y += __shfl_xor(acc0.y, 32);
    acc0.z += __shfl_xor(acc0.z, 16); acc0.z += __shfl_xor(acc0.z, 32);
    acc0.w += __shfl_xor(acc0.w, 16); acc0.w += __shfl_xor(acc0.w, 32);
    acc1.x += __shfl_xor(acc1.x, 16); acc1.x += __shfl_xor(acc1.x, 32);
    acc1.y += __shfl_xor(acc1.y, 16); acc1.y += __shfl_xor(acc1.y, 32);
    acc1.z += __shfl_xor(acc1.z, 16); acc1.z += __shfl_xor(acc1.z, 32);
    acc1.w += __shfl_xor(acc1.w, 16); acc1.w += __shfl_xor(acc1.w, 32);
    den += __shfl_xor(den, 16); den += __shfl_xor(den, 32);

    if (q == 0) {
        float4 r0 = {0.f, 0.f, 0.f, 0.f};
        float4 r1 = {0.f, 0.f, 0.f, 0.f};
        if (s1 > s0) {
            const float inv = 1.f / den;
            r0.x = acc0.x * inv; r0.y = acc0.y * inv;
            r0.z = acc0.z * inv; r0.w = acc0.w * inv;
            r1.x = acc1.x * inv; r1.y = acc1.y * inv;
            r1.z = acc1.z * inv; r1.w = acc1.w * inv;
        }
        // lane l holds d = 8l..8l+7
        ((float4*)(context + (size_t)f * DD))[2 * l]     = r0;
        ((float4*)(context + (size_t)f * DD))[2 * l + 1] = r1;
    }
}

// Stage 1: partial[sy][b][d] = sum over this slice's k of values[b][k]*context[k][d]
// grid: (4 b-tiles of 64, NSPLIT k-slices). Register tile 8b x 4d. NO atomics.
__global__ __launch_bounds__(256) void out_gemm_partial(
    const float* __restrict__ values, const float* __restrict__ context,
    float* __restrict__ partial)
{
    __shared__ float vl[64][64];    // 16KB values tile [b][k]
    __shared__ float xl[64][128];   // 32KB context tile [k][d]

    const int b0 = blockIdx.x * 64;
    const int sy = blockIdx.y;
    // k-range of this slice, in float4 units (5000 total; NF = 5000*4 exactly)
    const int s0_4 = (sy * 5000) >> 7;        // /NSPLIT
    const int s1_4 = ((sy + 1) * 5000) >> 7;
    const int t  = threadIdx.x;
    const int dg = t & 31;          // d = dg*4 .. dg*4+3
    const int bg = t >> 5;          // b = b0 + bg*8 .. +7

    float4 acc[8];
#pragma unroll
    for (int i = 0; i < 8; ++i) acc[i] = (float4){0.f, 0.f, 0.f, 0.f};

    for (int t4 = s0_4; t4 < s1_4; t4 += 16) {
        const int kt4 = min(16, s1_4 - t4);   // float4 units in this tile
        __syncthreads();
        // stage values tile: slots (bb, kq), kq in f4 units, coalesced along k
#pragma unroll
        for (int it = 0; it < 4; ++it) {
            int idx = t + it * 256;          // 0..1023
            int bb = idx >> 4;               // 0..63
            int kq = idx & 15;               // 0..15
            if (kq < kt4)
                *(float4*)&vl[bb][kq * 4] =
                    *(const float4*)&values[(size_t)(b0 + bb) * NF + (t4 + kq) * 4];
        }
        // stage context tile: rows kk (k within tile), coalesced along d
#pragma unroll
        for (int it = 0; it < 8; ++it) {
            int idx = t + it * 256;          // 0..2047
            int kk = idx >> 5;               // 0..63
            int c4 = (idx & 31) * 4;
            if (kk < kt4 * 4)
                *(float4*)&xl[kk][c4] =
                    *(const float4*)&context[(size_t)(t4 * 4 + kk) * DD + c4];
        }
        __syncthreads();

        for (int k4 = 0; k4 < kt4; ++k4) {
            const float4 xv0 = *(const float4*)&xl[k4 * 4 + 0][dg * 4];
            const float4 xv1 = *(const float4*)&xl[k4 * 4 + 1][dg * 4];
            const float4 xv2 = *(const float4*)&xl[k4 * 4 + 2][dg * 4];
            const float4 xv3 = *(const float4*)&xl[k4 * 4 + 3][dg * 4];
#pragma unroll
            for (int i = 0; i < 8; ++i) {
                const float4 vv = *(const float4*)&vl[bg * 8 + i][k4 * 4];
                acc[i].x = fmaf(vv.x, xv0.x, acc[i].x);
                acc[i].y = fmaf(vv.x, xv0.y, acc[i].y);
                acc[i].z = fmaf(vv.x, xv0.z, acc[i].z);
                acc[i].w = fmaf(vv.x, xv0.w, acc[i].w);
                acc[i].x = fmaf(vv.y, xv1.x, acc[i].x);
                acc[i].y = fmaf(vv.y, xv1.y, acc[i].y);
                acc[i].z = fmaf(vv.y, xv1.z, acc[i].z);
                acc[i].w = fmaf(vv.y, xv1.w, acc[i].w);
                acc[i].x = fmaf(vv.z, xv2.x, acc[i].x);
                acc[i].y = fmaf(vv.z, xv2.y, acc[i].y);
                acc[i].z = fmaf(vv.z, xv2.z, acc[i].z);
                acc[i].w = fmaf(vv.z, xv2.w, acc[i].w);
                acc[i].x = fmaf(vv.w, xv3.x, acc[i].x);
                acc[i].y = fmaf(vv.w, xv3.y, acc[i].y);
                acc[i].z = fmaf(vv.w, xv3.z, acc[i].z);
                acc[i].w = fmaf(vv.w, xv3.w, acc[i].w);
            }
        }
    }

    // private partial store — plain coalesced float4 stores, no contention
    float* pbase = partial + (size_t)sy * (NB * DD);
#pragma unroll
    for (int i = 0; i < 8; ++i)
        *(float4*)&pbase[(size_t)(b0 + bg * 8 + i) * DD + dg * 4] = acc[i];
}

// Stage 2: out[idx] = sum_s partial[s][idx]. One thread per output, no atomics.
__global__ __launch_bounds__(128) void out_reduce_kernel(
    const float* __restrict__ partial, float* __restrict__ out)
{
    const int idx = blockIdx.x * 128 + threadIdx.x;
    float s = 0.f;
#pragma unroll 8
    for (int p = 0; p < NSPLIT; ++p)
        s += partial[(size_t)p * (NB * DD) + idx];
    out[idx] = s;
}

// ---------------- launch ----------------

extern "C" void kernel_launch(void* const* d_in, const int* in_sizes, int n_in,
                              void* d_out, int out_size, void* d_ws, size_t ws_size,
                              hipStream_t stream) {
    const float* values   = (const float*)d_in[0];
    const float* feat_emb = (const float*)d_in[1];
    const float* hid_emb  = (const float*)d_in[2];
    const float* w_kernel = (const float*)d_in[3];
    const float* w_bias   = (const float*)d_in[4];
    const float* u_kernel = (const float*)d_in[5];
    const float* corr     = (const float*)d_in[6];
    const void*  cp_raw   = d_in[7];
    const void*  fci_raw  = d_in[8];
    float* out = (float*)d_out;

    char* ws = (char*)d_ws;
    size_t off = 0;
    auto alloc = [&](size_t bytes) {
        size_t cur = off;
        off += (bytes + 511) & ~size_t(511);
        return cur;
    };
    int*    flag    = (int*)   (ws + alloc(4));
    int*    cp32    = (int*)   (ws + alloc(sizeof(int) * NE));
    int*    fci32   = (int*)   (ws + alloc(sizeof(int) * NE));
    int*    offs    = (int*)   (ws + alloc(sizeof(int) * (NF + 1)));
    float*  P1      = (float*) (ws + alloc(sizeof(float) * (size_t)NF * AA));
    __half* P2h     = (__half*)(ws + alloc(sizeof(__half) * (size_t)NALL * AA));
    __half* embH    = (__half*)(ws + alloc(sizeof(__half) * (size_t)NALL * DD));
    __half* WtH     = (__half*)(ws + alloc(sizeof(__half) * 2 * 64 * 128));
    float*  context = (float*) (ws + alloc(sizeof(float) * (size_t)NF * DD));
    float*  partial = (float*) (ws + alloc(sizeof(float) * (size_t)NSPLIT * NB * DD));

    // 1. dtype probe + index conversion
    probe_kernel<<<1, 64, 0, stream>>>((const unsigned int*)fci_raw, flag);
    convert_kernel<<<(NE + 255) / 256, 256, 0, stream>>>(cp_raw, fci_raw, cp32, fci32, flag);

    // 2. fp16 tables: combined embedding + transposed weights
    prep_emb_kernel<<<(NALL * DD / 8) / 256, 256, 0, stream>>>(feat_emb, hid_emb, embH);
    prep_w_kernel<<<(2 * 64 * 128) / 256, 256, 0, stream>>>(w_kernel, WtH);

    // 3. segment offsets
    offsets_kernel<<<(NF + 1 + 255) / 256, 256, 0, stream>>>(cp32, offs);

    // 4. projections P1 / P2h via MFMA (5000 wave-tiles, 4 per block)
    proj_mfma_kernel<<<(NALL / 16 + NF / 16) / 4, 256, 0, stream>>>(
        embH, WtH, w_bias, P1, P2h);

    // 5. fused score + segment softmax + weighted aggregation -> context
    fused_agg_kernel<<<(NF + 3) / 4, 256, 0, stream>>>(embH, P1, P2h,
                                                       u_kernel, corr, offs, fci32,
                                                       context);

    // 6. out = values @ context  (atomic-free two-stage split-K)
    dim3 ggrid(NB / 64, NSPLIT);
    out_gemm_partial<<<ggrid, 256, 0, stream>>>(values, context, partial);
    out_reduce_kernel<<<(NB * DD) / 128, 128, 0, stream>>>(partial, out);
}